// Round 13
// baseline (387.138 us; speedup 1.0000x reference)
//
#include <hip/hip_runtime.h>
#include <hip/hip_bf16.h>
#include <hip/hip_fp8.h>

#define NN 50000
#define NE 800000
#define DIN 128
#define HC 256
#define NHEAD 4
#define CDIM 64
#define NGRAPH 512
#define NCLS 10
#define NEG_SLOPE 0.2f
#define NB 196   // ceil(NN/256)
#define NT1 3125 // NN/16 M-tiles

typedef __hip_bfloat16 bf16;
typedef __attribute__((ext_vector_type(8))) short short8;
typedef __attribute__((ext_vector_type(4))) float f32x4;

__device__ __forceinline__ float bf2f(unsigned short u) {
  union { unsigned int i; float f; } x;
  x.i = ((unsigned int)u) << 16;
  return x.f;
}
__device__ __forceinline__ unsigned short f2bf(float f) {
  bf16 v = __float2bfloat16(f);
  union { bf16 b; unsigned short s; } x;
  x.b = v;
  return x.s;
}
// fp8 e4m3 (OCP) encode/decode via HIP type
__device__ __forceinline__ unsigned char f2f8(float f) {
  __hip_fp8_e4m3 q(f);
  return (unsigned char)q.__x;
}
__device__ __forceinline__ float f82f(unsigned char u) {
  __hip_fp8_e4m3 q;
  q.__x = (__hip_fp8_storage_t)u;
  return (float)q;
}
__device__ __forceinline__ float lrelu(float x) { return x >= 0.f ? x : NEG_SLOPE * x; }
// NaN-propagating relu (fmaxf would silently clamp NaN to 0)
__device__ __forceinline__ float relu(float x) { return x < 0.f ? 0.f : x; }

// ---------------- zero scratch accumulators ----------------
__global__ void zero_kernel(int* __restrict__ p, int n) {
  int i = blockIdx.x * 256 + threadIdx.x;
  if (i < n) p[i] = 0;
}

// ---------------- repack W1,W2 (f32) into MFMA B-frag bf16 order ----------------
__global__ void repack_kernel(const float* __restrict__ W1, const float* __restrict__ W2,
                              unsigned short* __restrict__ W1p, unsigned short* __restrict__ W2p) {
  int i = blockIdx.x * 256 + threadIdx.x;
  if (i < 16 * 4 * 64 * 8) {  // W1: [128,256] -> ng(16) kk(4) lane(64) j(8)
    int j = i & 7, lane = (i >> 3) & 63, kk = (i >> 9) & 3, ng = i >> 11;
    int n = ng * 16 + (lane & 15);
    int k = kk * 32 + (lane >> 4) * 8 + j;
    W1p[i] = f2bf(W1[k * HC + n]);
  }
  int i2 = i - 16 * 4 * 64 * 8;
  if (i2 >= 0 && i2 < 4 * 8 * 64 * 8) {  // W2: [256,64] -> ng(4) kk(8) lane(64) j(8)
    int j = i2 & 7, lane = (i2 >> 3) & 63, kk = (i2 >> 9) & 7, ng = i2 >> 12;
    int n = ng * 16 + (lane & 15);
    int k = kk * 32 + (lane >> 4) * 8 + j;
    W2p[i2] = f2bf(W2[k * CDIM + n]);
  }
}

// ---------------- GEMM1 + fused als1/ald1: h1 = bf16(x) @ W1  (bf16 MFMA) ------------
__global__ __launch_bounds__(256) void gemm1_kernel(const float* __restrict__ x,
                                                    const unsigned short* __restrict__ W1p,
                                                    const float* __restrict__ a_src,
                                                    const float* __restrict__ a_dst,
                                                    unsigned short* __restrict__ h1,
                                                    float* __restrict__ als,
                                                    float* __restrict__ ald) {
  __shared__ float sh_as[HC], sh_ad[HC];
  {
    int t = threadIdx.x;
    sh_as[t] = a_src[t];
    sh_ad[t] = a_dst[t];
  }
  __syncthreads();
  int wave = threadIdx.x >> 6, lane = threadIdx.x & 63;
  int tile = blockIdx.x * 4 + wave;
  if (tile >= NT1) return;
  int r0 = tile * 16, m = lane & 15, quad = lane >> 4;
  int row = r0 + m;
  short8 a[4];
#pragma unroll
  for (int kk = 0; kk < 4; kk++) {
    int kb = kk * 32 + quad * 8;
    float4 f0 = *(const float4*)(x + row * DIN + kb);
    float4 f1 = *(const float4*)(x + row * DIN + kb + 4);
    alignas(16) unsigned short tmp[8];
    tmp[0] = f2bf(f0.x); tmp[1] = f2bf(f0.y); tmp[2] = f2bf(f0.z); tmp[3] = f2bf(f0.w);
    tmp[4] = f2bf(f1.x); tmp[5] = f2bf(f1.y); tmp[6] = f2bf(f1.z); tmp[7] = f2bf(f1.w);
    a[kk] = *(const short8*)tmp;
  }
#pragma unroll
  for (int hg = 0; hg < 4; hg++) {
    float ps[4] = {0.f, 0.f, 0.f, 0.f};
    float pd[4] = {0.f, 0.f, 0.f, 0.f};
#pragma unroll
    for (int sub = 0; sub < 4; sub++) {
      int ng = hg * 4 + sub;
      f32x4 acc = {0.f, 0.f, 0.f, 0.f};
#pragma unroll
      for (int kk = 0; kk < 4; kk++) {
        short8 b = *(const short8*)(W1p + ((ng * 4 + kk) * 64 + lane) * 8);
        acc = __builtin_amdgcn_mfma_f32_16x16x32_bf16(a[kk], b, acc, 0, 0, 0);
      }
      int col = ng * 16 + m;
      float asv = sh_as[col], adv = sh_ad[col];
#pragma unroll
      for (int r = 0; r < 4; r++) {
        h1[(r0 + quad * 4 + r) * HC + col] = f2bf(acc[r]);
        ps[r] += acc[r] * asv;
        pd[r] += acc[r] * adv;
      }
    }
#pragma unroll
    for (int o = 1; o < 16; o <<= 1) {
#pragma unroll
      for (int r = 0; r < 4; r++) {
        ps[r] += __shfl_xor(ps[r], o, 64);
        pd[r] += __shfl_xor(pd[r], o, 64);
      }
    }
    if (m == 0) {
#pragma unroll
      for (int r = 0; r < 4; r++) {
        int rr = r0 + quad * 4 + r;
        als[rr * NHEAD + hg] = ps[r];
        ald[rr * NHEAD + hg] = pd[r];
      }
    }
  }
}

// ---------------- bf16 -> fp8 shadow copy of h1 for the gather path ----------------
__global__ void cvt1_kernel(const unsigned short* __restrict__ h1,
                            unsigned char* __restrict__ h1f8) {
  int i = blockIdx.x * 256 + threadIdx.x;  // i < NN*HC/4
  ushort4 v = ((const ushort4*)h1)[i];
  uchar4 o;
  o.x = f2f8(bf2f(v.x));
  o.y = f2f8(bf2f(v.y));
  o.z = f2f8(bf2f(v.z));
  o.w = f2f8(bf2f(v.w));
  ((uchar4*)h1f8)[i] = o;
}

// ---------------- edge histogram (deg by dst, 8-way sharded by e&7) ----------------
__global__ void hist_kernel(const int* __restrict__ ei, int* __restrict__ deg8) {
  int i = blockIdx.x * 256 + threadIdx.x;
  if (i < NE) atomicAdd(&deg8[(i & 7) * NN + ei[NE + i]], 1);
}

// ---------------- exclusive scan of deg -> off, sharded cursors ----------------
__global__ void scan_a(const int* __restrict__ deg8, int* __restrict__ bsum,
                       int* __restrict__ degsum) {
  __shared__ int sm[256];
  int t = threadIdx.x, i = blockIdx.x * 256 + t;
  int d = 0;
  if (i < NN) {
#pragma unroll
    for (int j = 0; j < 8; j++) d += deg8[j * NN + i];
    degsum[i] = d;
  }
  sm[t] = d;
  __syncthreads();
  for (int s = 128; s > 0; s >>= 1) {
    if (t < s) sm[t] += sm[t + s];
    __syncthreads();
  }
  if (t == 0) bsum[blockIdx.x] = sm[0];
}
__global__ void scan_b(const int* __restrict__ bsum, int* __restrict__ bscan) {
  __shared__ int sm[256];
  int t = threadIdx.x;
  int own = (t < NB) ? bsum[t] : 0;
  sm[t] = own;
  __syncthreads();
  for (int s = 1; s < 256; s <<= 1) {
    int v = (t >= s) ? sm[t - s] : 0;
    __syncthreads();
    sm[t] += v;
    __syncthreads();
  }
  if (t < NB) bscan[t] = sm[t] - own;  // exclusive over block sums
}
__global__ void scan_c(const int* __restrict__ degsum, const int* __restrict__ deg8,
                       const int* __restrict__ bscan,
                       int* __restrict__ off, int* __restrict__ cursor8) {
  __shared__ int sm[256];
  int t = threadIdx.x, i = blockIdx.x * 256 + t;
  int d = (i < NN) ? degsum[i] : 0;
  sm[t] = d;
  __syncthreads();
  for (int s = 1; s < 256; s <<= 1) {
    int v = (t >= s) ? sm[t - s] : 0;
    __syncthreads();
    sm[t] += v;
    __syncthreads();
  }
  int excl = bscan[blockIdx.x] + sm[t] - d;
  if (i < NN) {
    off[i] = excl;
    int base = excl;
#pragma unroll
    for (int j = 0; j < 8; j++) {
      cursor8[j * NN + i] = base;
      base += deg8[j * NN + i];
    }
    if (i == NN - 1) off[NN] = excl + d;
  }
}

// ---------------- scatter edges into CSR: sharded cursor (contention /8) -------------
__global__ void scatter_kernel(const int* __restrict__ ei, int* __restrict__ cursor8,
                               int2* __restrict__ epair) {
  int e = blockIdx.x * 256 + threadIdx.x;
  if (e >= NE) return;
  int s = ei[e];
  int d = ei[NE + e];
  int p = atomicAdd(&cursor8[(e & 7) * NN + d], 1);
  epair[p] = make_int2(s, d);
}

// ---------------- layer1 edge weights + dense esrc, CSR order, coalesced -------------
__global__ void ew1_kernel(const int2* __restrict__ epair,
                           const float* __restrict__ als, const float* __restrict__ ald,
                           float* __restrict__ ew, int* __restrict__ esrc) {
  int k = blockIdx.x * 256 + threadIdx.x;
  if (k >= NE) return;
  int2 e = epair[k];
  esrc[k] = e.x;
  float4 as = *(const float4*)(als + e.x * 4);
  float4 ad = *(const float4*)(ald + e.y * 4);
  float4 w;
  w.x = __expf(lrelu(as.x + ad.x));
  w.y = __expf(lrelu(as.y + ad.y));
  w.z = __expf(lrelu(as.z + ad.z));
  w.w = __expf(lrelu(as.w + ad.w));
  *(float4*)(ew + k * 4) = w;
}

// ---------------- GAT layer1 aggregation: wave/node, fp8, 16 edges/iter --------------
// lane -> edge-group eg=lane>>5 (2 groups), channels c0=(lane&31)*8 (8 ch, head c0>>6).
__global__ __launch_bounds__(256) void agg1_kernel(const unsigned short* __restrict__ h1,
                                                   const unsigned char* __restrict__ h1f8,
                                                   const float* __restrict__ als,
                                                   const float* __restrict__ ald,
                                                   const int* __restrict__ off,
                                                   const int* __restrict__ esrc,
                                                   const float* __restrict__ ew,
                                                   const float* __restrict__ b1,
                                                   unsigned short* __restrict__ out1) {
  int node = blockIdx.x * 4 + (threadIdx.x >> 6);
  int lane = threadIdx.x & 63;
  int eg = lane >> 5;
  int c0 = (lane & 31) * 8;
  int hh = c0 >> 6;
  int beg = off[node], end = off[node + 1];
  float a[8] = {0.f, 0.f, 0.f, 0.f, 0.f, 0.f, 0.f, 0.f};
  float zz = 0.f;
  int k = beg;
  for (; k + 15 < end; k += 16) {
    int idx[8];
    int s[8];
    float w[8];
    uint2 u[8];
#pragma unroll
    for (int j = 0; j < 8; j++) idx[j] = k + 2 * j + eg;
#pragma unroll
    for (int j = 0; j < 8; j++) s[j] = esrc[idx[j]];
#pragma unroll
    for (int j = 0; j < 8; j++) {
      w[j] = ew[idx[j] * 4 + hh];
      u[j] = *(const uint2*)(h1f8 + s[j] * HC + c0);
    }
#pragma unroll
    for (int j = 0; j < 8; j++) {
#pragma unroll
      for (int q = 0; q < 4; q++) {
        a[q] += w[j] * f82f((u[j].x >> (8 * q)) & 0xff);
        a[q + 4] += w[j] * f82f((u[j].y >> (8 * q)) & 0xff);
      }
      zz += w[j];
    }
  }
  for (; k + 7 < end; k += 8) {
    int i0 = k + eg, i1 = k + 2 + eg, i2 = k + 4 + eg, i3 = k + 6 + eg;
    int s0 = esrc[i0], s1 = esrc[i1], s2 = esrc[i2], s3 = esrc[i3];
    float w0 = ew[i0 * 4 + hh], w1 = ew[i1 * 4 + hh];
    float w2 = ew[i2 * 4 + hh], w3 = ew[i3 * 4 + hh];
    uint2 u0 = *(const uint2*)(h1f8 + s0 * HC + c0);
    uint2 u1 = *(const uint2*)(h1f8 + s1 * HC + c0);
    uint2 u2 = *(const uint2*)(h1f8 + s2 * HC + c0);
    uint2 u3 = *(const uint2*)(h1f8 + s3 * HC + c0);
#pragma unroll
    for (int j = 0; j < 4; j++) {
      a[j] += w0 * f82f((u0.x >> (8 * j)) & 0xff) + w1 * f82f((u1.x >> (8 * j)) & 0xff)
            + w2 * f82f((u2.x >> (8 * j)) & 0xff) + w3 * f82f((u3.x >> (8 * j)) & 0xff);
      a[j + 4] += w0 * f82f((u0.y >> (8 * j)) & 0xff) + w1 * f82f((u1.y >> (8 * j)) & 0xff)
                + w2 * f82f((u2.y >> (8 * j)) & 0xff) + w3 * f82f((u3.y >> (8 * j)) & 0xff);
    }
    zz += w0 + w1 + w2 + w3;
  }
  for (; k < end; k += 2) {
    int i0 = k + eg;
    if (i0 < end) {
      int s0 = esrc[i0];
      float w0 = ew[i0 * 4 + hh];
      uint2 u0 = *(const uint2*)(h1f8 + s0 * HC + c0);
#pragma unroll
      for (int j = 0; j < 4; j++) {
        a[j] += w0 * f82f((u0.x >> (8 * j)) & 0xff);
        a[j + 4] += w0 * f82f((u0.y >> (8 * j)) & 0xff);
      }
      zz += w0;
    }
  }
  // combine the two edge-groups (lanes L and L^32 cover the same channels)
#pragma unroll
  for (int j = 0; j < 8; j++) a[j] += __shfl_xor(a[j], 32, 64);
  zz += __shfl_xor(zz, 32, 64);
  if (eg == 0) {
    // self-loop from bf16 original
    float sw = __expf(lrelu(als[node * NHEAD + hh] + ald[node * NHEAD + hh]));
    ushort4 vs0 = *(const ushort4*)(h1 + node * HC + c0);
    ushort4 vs1 = *(const ushort4*)(h1 + node * HC + c0 + 4);
    a[0] += sw * bf2f(vs0.x); a[1] += sw * bf2f(vs0.y);
    a[2] += sw * bf2f(vs0.z); a[3] += sw * bf2f(vs0.w);
    a[4] += sw * bf2f(vs1.x); a[5] += sw * bf2f(vs1.y);
    a[6] += sw * bf2f(vs1.z); a[7] += sw * bf2f(vs1.w);
    zz += sw;
    float inv = 1.f / zz;
    float4 bb0 = *(const float4*)(b1 + c0);
    float4 bb1 = *(const float4*)(b1 + c0 + 4);
    ushort4 o0, o1;
    o0.x = f2bf(a[0] * inv + bb0.x); o0.y = f2bf(a[1] * inv + bb0.y);
    o0.z = f2bf(a[2] * inv + bb0.z); o0.w = f2bf(a[3] * inv + bb0.w);
    o1.x = f2bf(a[4] * inv + bb1.x); o1.y = f2bf(a[5] * inv + bb1.y);
    o1.z = f2bf(a[6] * inv + bb1.z); o1.w = f2bf(a[7] * inv + bb1.w);
    *(ushort4*)(out1 + node * HC + c0) = o0;
    *(ushort4*)(out1 + node * HC + c0 + 4) = o1;
  }
}

// ---------------- BN stats over out1 ----------------
__global__ __launch_bounds__(256) void bnstats_kernel(const unsigned short* __restrict__ out1,
                                                      float* __restrict__ bnsum,
                                                      float* __restrict__ bnsumsq) {
  int t = threadIdx.x;
  float s = 0.f, s2 = 0.f;
  for (int r = blockIdx.x; r < NN; r += gridDim.x) {
    float v = bf2f(out1[r * HC + t]);
    s += v;
    s2 += v * v;
  }
  atomicAdd(&bnsum[t], s);
  atomicAdd(&bnsumsq[t], s2);
}

// ---------------- GEMM2 + fused als2/ald2: h2 = relu(bn(out1)) @ W2 ------------------
__global__ __launch_bounds__(256) void gemm2_kernel(const unsigned short* __restrict__ out1,
                                                    const unsigned short* __restrict__ W2p,
                                                    const float* __restrict__ bnsum,
                                                    const float* __restrict__ bnsumsq,
                                                    const float* __restrict__ gamma,
                                                    const float* __restrict__ beta,
                                                    const float* __restrict__ a_src2,
                                                    const float* __restrict__ a_dst2,
                                                    unsigned short* __restrict__ h2,
                                                    float* __restrict__ als2,
                                                    float* __restrict__ ald2) {
  __shared__ float scale_s[HC], shift_s[HC];
  __shared__ float sh_as[CDIM], sh_ad[CDIM];
  {
    int t = threadIdx.x;
    float mu = bnsum[t] / (float)NN;
    float var = bnsumsq[t] / (float)NN - mu * mu;
    float sc = gamma[t] * rsqrtf(var + 1e-5f);
    scale_s[t] = sc;
    shift_s[t] = beta[t] - mu * sc;
    if (t < CDIM) {
      sh_as[t] = a_src2[t];
      sh_ad[t] = a_dst2[t];
    }
  }
  __syncthreads();
  int wave = threadIdx.x >> 6, lane = threadIdx.x & 63;
  int tile = blockIdx.x * 4 + wave;
  if (tile >= NT1) return;
  int r0 = tile * 16, m = lane & 15, quad = lane >> 4;
  int row = r0 + m;
  short8 a[8];
#pragma unroll
  for (int kk = 0; kk < 8; kk++) {
    int kb = kk * 32 + quad * 8;
    short8 raw = *(const short8*)(out1 + row * HC + kb);
    alignas(16) unsigned short tmp[8];
#pragma unroll
    for (int j = 0; j < 8; j++) {
      tmp[j] = f2bf(relu(bf2f((unsigned short)raw[j]) * scale_s[kb + j] + shift_s[kb + j]));
    }
    a[kk] = *(const short8*)tmp;
  }
  float ps[4] = {0.f, 0.f, 0.f, 0.f};
  float pd[4] = {0.f, 0.f, 0.f, 0.f};
#pragma unroll
  for (int ng = 0; ng < 4; ng++) {
    f32x4 acc = {0.f, 0.f, 0.f, 0.f};
#pragma unroll
    for (int kk = 0; kk < 8; kk++) {
      short8 b = *(const short8*)(W2p + ((ng * 8 + kk) * 64 + lane) * 8);
      acc = __builtin_amdgcn_mfma_f32_16x16x32_bf16(a[kk], b, acc, 0, 0, 0);
    }
    int col = ng * 16 + m;
    float asv = sh_as[col], adv = sh_ad[col];
#pragma unroll
    for (int r = 0; r < 4; r++) {
      h2[(r0 + quad * 4 + r) * CDIM + col] = f2bf(acc[r]);
      ps[r] += acc[r] * asv;
      pd[r] += acc[r] * adv;
    }
  }
#pragma unroll
  for (int o = 1; o < 16; o <<= 1) {
#pragma unroll
    for (int r = 0; r < 4; r++) {
      ps[r] += __shfl_xor(ps[r], o, 64);
      pd[r] += __shfl_xor(pd[r], o, 64);
    }
  }
  if (m == 0) {
#pragma unroll
    for (int r = 0; r < 4; r++) {
      int rr = r0 + quad * 4 + r;
      als2[rr] = ps[r];
      ald2[rr] = pd[r];
    }
  }
}

// ---------------- layer2 edge weights, CSR order, coalesced ----------------
__global__ void ew2_kernel(const int2* __restrict__ epair,
                           const float* __restrict__ als2, const float* __restrict__ ald2,
                           float* __restrict__ ew2) {
  int k = blockIdx.x * 256 + threadIdx.x;
  if (k >= NE) return;
  int2 e = epair[k];
  ew2[k] = __expf(lrelu(als2[e.x] + ald2[e.y]));
}

// ---------------- GAT layer2 agg + ReLU + pooling: wave/node, half-split, 16-deep ----
__global__ __launch_bounds__(256) void agg2_kernel(const unsigned short* __restrict__ h2,
                                                   const float* __restrict__ als2,
                                                   const float* __restrict__ ald2,
                                                   const int* __restrict__ off,
                                                   const int* __restrict__ esrc,
                                                   const float* __restrict__ ew2,
                                                   const float* __restrict__ b2,
                                                   const int* __restrict__ batch,
                                                   float* __restrict__ pooled) {
  int node = blockIdx.x * 4 + (threadIdx.x >> 6);
  int lane = threadIdx.x & 63;
  int half = lane >> 5;
  int cp = (lane & 31) * 2;
  int beg = off[node], end = off[node + 1];
  float a0 = 0.f, a1 = 0.f, zz = 0.f;
  int k = beg;
  for (; k + 15 < end; k += 16) {
    int idx[8];
    int s[8];
    float w[8];
    ushort2 v[8];
#pragma unroll
    for (int j = 0; j < 8; j++) idx[j] = k + 2 * j + half;
#pragma unroll
    for (int j = 0; j < 8; j++) s[j] = esrc[idx[j]];
#pragma unroll
    for (int j = 0; j < 8; j++) {
      w[j] = ew2[idx[j]];
      v[j] = *(const ushort2*)(h2 + s[j] * CDIM + cp);
    }
#pragma unroll
    for (int j = 0; j < 8; j++) {
      a0 += w[j] * bf2f(v[j].x);
      a1 += w[j] * bf2f(v[j].y);
      zz += w[j];
    }
  }
  for (; k + 7 < end; k += 8) {
    int i0 = k + half, i1 = k + 2 + half, i2 = k + 4 + half, i3 = k + 6 + half;
    int s0 = esrc[i0], s1 = esrc[i1], s2 = esrc[i2], s3 = esrc[i3];
    float w0 = ew2[i0], w1 = ew2[i1], w2 = ew2[i2], w3 = ew2[i3];
    ushort2 v0 = *(const ushort2*)(h2 + s0 * CDIM + cp);
    ushort2 v1 = *(const ushort2*)(h2 + s1 * CDIM + cp);
    ushort2 v2 = *(const ushort2*)(h2 + s2 * CDIM + cp);
    ushort2 v3 = *(const ushort2*)(h2 + s3 * CDIM + cp);
    a0 += w0 * bf2f(v0.x) + w1 * bf2f(v1.x) + w2 * bf2f(v2.x) + w3 * bf2f(v3.x);
    a1 += w0 * bf2f(v0.y) + w1 * bf2f(v1.y) + w2 * bf2f(v2.y) + w3 * bf2f(v3.y);
    zz += w0 + w1 + w2 + w3;
  }
  for (; k < end; k += 2) {
    int i0 = k + half;
    if (i0 < end) {
      int s0 = esrc[i0];
      float w0 = ew2[i0];
      ushort2 v0 = *(const ushort2*)(h2 + s0 * CDIM + cp);
      a0 += w0 * bf2f(v0.x);
      a1 += w0 * bf2f(v0.y);
      zz += w0;
    }
  }
  // combine the two halves (lanes L and L^32 cover the same channel pair)
  a0 += __shfl_xor(a0, 32, 64);
  a1 += __shfl_xor(a1, 32, 64);
  zz += __shfl_xor(zz, 32, 64);
  if (half == 0) {
    float sw = __expf(lrelu(als2[node] + ald2[node]));
    ushort2 vs = *(const ushort2*)(h2 + node * CDIM + cp);
    a0 += sw * bf2f(vs.x);
    a1 += sw * bf2f(vs.y);
    zz += sw;
    float inv = 1.f / zz;
    int g = batch[node];
    float v0 = relu(a0 * inv + b2[cp]);
    float v1 = relu(a1 * inv + b2[cp + 1]);
    atomicAdd(&pooled[g * CDIM + cp], v0);
    atomicAdd(&pooled[g * CDIM + cp + 1], v1);
  }
}

// ---------------- pooled mean + classifier (f32 output); counts via binary search ----
__global__ void cls_kernel(const float* __restrict__ pooled, const int* __restrict__ batch,
                           const float* __restrict__ cW1, const float* __restrict__ cb1,
                           const float* __restrict__ cW2, const float* __restrict__ cb2,
                           float* __restrict__ out) {
  __shared__ float p[64];
  __shared__ float z[32];
  int g = blockIdx.x, t = threadIdx.x;
  int lo = 0, hi = NN;
  while (lo < hi) { int mid = (lo + hi) >> 1; if (batch[mid] < g) lo = mid + 1; else hi = mid; }
  int start = lo;
  lo = 0; hi = NN;
  while (lo < hi) { int mid = (lo + hi) >> 1; if (batch[mid] <= g) lo = mid + 1; else hi = mid; }
  int c = lo - start;
  float cnt = (float)(c > 0 ? c : 1);
  p[t] = pooled[g * CDIM + t] / cnt;
  __syncthreads();
  if (t < 32) {
    float a = cb1[t];
    for (int k = 0; k < 64; k++) a += p[k] * cW1[k * 32 + t];
    z[t] = relu(a);
  }
  __syncthreads();
  if (t < NCLS) {
    float a = cb2[t];
    for (int k = 0; k < 32; k++) a += z[k] * cW2[k * NCLS + t];
    out[g * NCLS + t] = a;
  }
}

extern "C" void kernel_launch(void* const* d_in, const int* in_sizes, int n_in,
                              void* d_out, int out_size, void* d_ws, size_t ws_size,
                              hipStream_t stream) {
  const float* x = (const float*)d_in[0];
  const int* edge_index = (const int*)d_in[1];
  const int* batch = (const int*)d_in[2];
  const float* W1 = (const float*)d_in[3];
  const float* a_src1 = (const float*)d_in[4];
  const float* a_dst1 = (const float*)d_in[5];
  const float* b1 = (const float*)d_in[6];
  const float* gamma = (const float*)d_in[7];
  const float* beta = (const float*)d_in[8];
  const float* W2 = (const float*)d_in[9];
  const float* a_src2 = (const float*)d_in[10];
  const float* a_dst2 = (const float*)d_in[11];
  const float* b2 = (const float*)d_in[12];
  const float* cW1 = (const float*)d_in[13];
  const float* cb1 = (const float*)d_in[14];
  const float* cW2 = (const float*)d_in[15];
  const float* cb2 = (const float*)d_in[16];

  // ---- workspace layout ----
  // zero region (contiguous, zeroed every call): deg8 | bnsum | bnsumsq | pooled
  int* deg8 = (int*)d_ws;
  float* bnsum = (float*)(deg8 + 8 * NN);
  float* bnsumsq = bnsum + HC;
  float* pooled = bnsumsq + HC;
  const int ZWORDS = 8 * NN + HC + HC + NGRAPH * CDIM;
  char* p = (char*)(pooled + NGRAPH * CDIM);
  auto align256 = [&](char*& q) {
    size_t a = (size_t)(q - (char*)d_ws);
    a = (a + 255) & ~(size_t)255;
    q = (char*)d_ws + a;
  };
  align256(p);
  int* degsum = (int*)p;          p += (size_t)NN * 4;       align256(p);
  int* offs = (int*)p;            p += (size_t)(NN + 1) * 4; align256(p);
  int* cursor8 = (int*)p;         p += (size_t)8 * NN * 4;   align256(p);
  int2* epair = (int2*)p;         p += (size_t)NE * 8;       align256(p);
  int* esrc = (int*)p;            p += (size_t)NE * 4;       align256(p);
  int* bsum = (int*)p;            p += 256 * 4;              align256(p);
  int* bscan = (int*)p;           p += 256 * 4;              align256(p);
  // h1 region; ew2 (NE*4 = 3.2MB) aliases its head: h1 dead after agg1, ew2 written later
  unsigned short* h1 = (unsigned short*)p;
  float* ew2 = (float*)p;         p += (size_t)NN * HC * 2;   align256(p);
  unsigned short* out1 = (unsigned short*)p; p += (size_t)NN * HC * 2;   align256(p);
  unsigned short* h2 = (unsigned short*)p;   p += (size_t)NN * CDIM * 2; align256(p);
  float* als1 = (float*)p;        p += (size_t)NN * NHEAD * 4; align256(p);
  float* ald1 = (float*)p;        p += (size_t)NN * NHEAD * 4; align256(p);
  float* als2v = (float*)p;       p += (size_t)NN * 4;         align256(p);
  float* ald2v = (float*)p;       p += (size_t)NN * 4;         align256(p);
  float* ew1 = (float*)p;         p += (size_t)NE * NHEAD * 4; align256(p);
  unsigned char* h1f8 = (unsigned char*)p; p += (size_t)NN * HC;        align256(p);
  unsigned short* W1p = (unsigned short*)p; p += 32768 * 2;    align256(p);
  unsigned short* W2p = (unsigned short*)p; p += 16384 * 2;    align256(p);

  zero_kernel<<<(ZWORDS + 255) / 256, 256, 0, stream>>>((int*)d_ws, ZWORDS);
  repack_kernel<<<192, 256, 0, stream>>>(W1, W2, W1p, W2p);
  gemm1_kernel<<<(NT1 + 3) / 4, 256, 0, stream>>>(x, W1p, a_src1, a_dst1, h1, als1, ald1);
  cvt1_kernel<<<NN * HC / 4 / 256, 256, 0, stream>>>(h1, h1f8);
  hist_kernel<<<(NE + 255) / 256, 256, 0, stream>>>(edge_index, deg8);
  scan_a<<<NB, 256, 0, stream>>>(deg8, bsum, degsum);
  scan_b<<<1, 256, 0, stream>>>(bsum, bscan);
  scan_c<<<NB, 256, 0, stream>>>(degsum, deg8, bscan, offs, cursor8);
  scatter_kernel<<<(NE + 255) / 256, 256, 0, stream>>>(edge_index, cursor8, epair);
  ew1_kernel<<<(NE + 255) / 256, 256, 0, stream>>>(epair, als1, ald1, ew1, esrc);
  agg1_kernel<<<NN / 4, 256, 0, stream>>>(h1, h1f8, als1, ald1, offs, esrc, ew1, b1, out1);
  bnstats_kernel<<<1024, 256, 0, stream>>>(out1, bnsum, bnsumsq);
  gemm2_kernel<<<(NT1 + 3) / 4, 256, 0, stream>>>(out1, W2p, bnsum, bnsumsq, gamma, beta,
                                                  a_src2, a_dst2, h2, als2v, ald2v);
  ew2_kernel<<<(NE + 255) / 256, 256, 0, stream>>>(epair, als2v, ald2v, ew2);
  agg2_kernel<<<NN / 4, 256, 0, stream>>>(h2, als2v, ald2v, offs, esrc, ew2, b2,
                                          batch, pooled);
  cls_kernel<<<NGRAPH, 64, 0, stream>>>(pooled, batch, cW1, cb1, cW2, cb2, (float*)d_out);
}

// Round 14
// 365.720 us; speedup vs baseline: 1.0586x; 1.0586x over previous
//
#include <hip/hip_runtime.h>
#include <hip/hip_bf16.h>
#include <hip/hip_fp8.h>

#define NN 50000
#define NE 800000
#define DIN 128
#define HC 256
#define NHEAD 4
#define CDIM 64
#define NGRAPH 512
#define NCLS 10
#define NEG_SLOPE 0.2f
#define NB 196   // ceil(NN/256)
#define NT1 3125 // NN/16 M-tiles

typedef __hip_bfloat16 bf16;
typedef __attribute__((ext_vector_type(8))) short short8;
typedef __attribute__((ext_vector_type(4))) float f32x4;

__device__ __forceinline__ float bf2f(unsigned short u) {
  union { unsigned int i; float f; } x;
  x.i = ((unsigned int)u) << 16;
  return x.f;
}
__device__ __forceinline__ unsigned short f2bf(float f) {
  bf16 v = __float2bfloat16(f);
  union { bf16 b; unsigned short s; } x;
  x.b = v;
  return x.s;
}
// fp8 e4m3 (OCP) encode/decode via HIP type
__device__ __forceinline__ unsigned char f2f8(float f) {
  __hip_fp8_e4m3 q(f);
  return (unsigned char)q.__x;
}
__device__ __forceinline__ float f82f(unsigned char u) {
  __hip_fp8_e4m3 q;
  q.__x = (__hip_fp8_storage_t)u;
  return (float)q;
}
__device__ __forceinline__ float lrelu(float x) { return x >= 0.f ? x : NEG_SLOPE * x; }
// NaN-propagating relu (fmaxf would silently clamp NaN to 0)
__device__ __forceinline__ float relu(float x) { return x < 0.f ? 0.f : x; }

// ---------------- zero scratch accumulators ----------------
__global__ void zero_kernel(int* __restrict__ p, int n) {
  int i = blockIdx.x * 256 + threadIdx.x;
  if (i < n) p[i] = 0;
}

// ---------------- repack W1,W2 (f32) into MFMA B-frag bf16 order ----------------
__global__ void repack_kernel(const float* __restrict__ W1, const float* __restrict__ W2,
                              unsigned short* __restrict__ W1p, unsigned short* __restrict__ W2p) {
  int i = blockIdx.x * 256 + threadIdx.x;
  if (i < 16 * 4 * 64 * 8) {  // W1: [128,256] -> ng(16) kk(4) lane(64) j(8)
    int j = i & 7, lane = (i >> 3) & 63, kk = (i >> 9) & 3, ng = i >> 11;
    int n = ng * 16 + (lane & 15);
    int k = kk * 32 + (lane >> 4) * 8 + j;
    W1p[i] = f2bf(W1[k * HC + n]);
  }
  int i2 = i - 16 * 4 * 64 * 8;
  if (i2 >= 0 && i2 < 4 * 8 * 64 * 8) {  // W2: [256,64] -> ng(4) kk(8) lane(64) j(8)
    int j = i2 & 7, lane = (i2 >> 3) & 63, kk = (i2 >> 9) & 7, ng = i2 >> 12;
    int n = ng * 16 + (lane & 15);
    int k = kk * 32 + (lane >> 4) * 8 + j;
    W2p[i2] = f2bf(W2[k * CDIM + n]);
  }
}

// ---------------- GEMM1 + fused als1/ald1: h1 = bf16(x) @ W1  (bf16 MFMA) ------------
__global__ __launch_bounds__(256) void gemm1_kernel(const float* __restrict__ x,
                                                    const unsigned short* __restrict__ W1p,
                                                    const float* __restrict__ a_src,
                                                    const float* __restrict__ a_dst,
                                                    unsigned short* __restrict__ h1,
                                                    float* __restrict__ als,
                                                    float* __restrict__ ald) {
  __shared__ float sh_as[HC], sh_ad[HC];
  {
    int t = threadIdx.x;
    sh_as[t] = a_src[t];
    sh_ad[t] = a_dst[t];
  }
  __syncthreads();
  int wave = threadIdx.x >> 6, lane = threadIdx.x & 63;
  int tile = blockIdx.x * 4 + wave;
  if (tile >= NT1) return;
  int r0 = tile * 16, m = lane & 15, quad = lane >> 4;
  int row = r0 + m;
  short8 a[4];
#pragma unroll
  for (int kk = 0; kk < 4; kk++) {
    int kb = kk * 32 + quad * 8;
    float4 f0 = *(const float4*)(x + row * DIN + kb);
    float4 f1 = *(const float4*)(x + row * DIN + kb + 4);
    alignas(16) unsigned short tmp[8];
    tmp[0] = f2bf(f0.x); tmp[1] = f2bf(f0.y); tmp[2] = f2bf(f0.z); tmp[3] = f2bf(f0.w);
    tmp[4] = f2bf(f1.x); tmp[5] = f2bf(f1.y); tmp[6] = f2bf(f1.z); tmp[7] = f2bf(f1.w);
    a[kk] = *(const short8*)tmp;
  }
#pragma unroll
  for (int hg = 0; hg < 4; hg++) {
    float ps[4] = {0.f, 0.f, 0.f, 0.f};
    float pd[4] = {0.f, 0.f, 0.f, 0.f};
#pragma unroll
    for (int sub = 0; sub < 4; sub++) {
      int ng = hg * 4 + sub;
      f32x4 acc = {0.f, 0.f, 0.f, 0.f};
#pragma unroll
      for (int kk = 0; kk < 4; kk++) {
        short8 b = *(const short8*)(W1p + ((ng * 4 + kk) * 64 + lane) * 8);
        acc = __builtin_amdgcn_mfma_f32_16x16x32_bf16(a[kk], b, acc, 0, 0, 0);
      }
      int col = ng * 16 + m;
      float asv = sh_as[col], adv = sh_ad[col];
#pragma unroll
      for (int r = 0; r < 4; r++) {
        h1[(r0 + quad * 4 + r) * HC + col] = f2bf(acc[r]);
        ps[r] += acc[r] * asv;
        pd[r] += acc[r] * adv;
      }
    }
#pragma unroll
    for (int o = 1; o < 16; o <<= 1) {
#pragma unroll
      for (int r = 0; r < 4; r++) {
        ps[r] += __shfl_xor(ps[r], o, 64);
        pd[r] += __shfl_xor(pd[r], o, 64);
      }
    }
    if (m == 0) {
#pragma unroll
      for (int r = 0; r < 4; r++) {
        int rr = r0 + quad * 4 + r;
        als[rr * NHEAD + hg] = ps[r];
        ald[rr * NHEAD + hg] = pd[r];
      }
    }
  }
}

// ---------------- bf16 -> fp8 shadow copy of h1 for the gather path ----------------
__global__ void cvt1_kernel(const unsigned short* __restrict__ h1,
                            unsigned char* __restrict__ h1f8) {
  int i = blockIdx.x * 256 + threadIdx.x;  // i < NN*HC/4
  ushort4 v = ((const ushort4*)h1)[i];
  uchar4 o;
  o.x = f2f8(bf2f(v.x));
  o.y = f2f8(bf2f(v.y));
  o.z = f2f8(bf2f(v.z));
  o.w = f2f8(bf2f(v.w));
  ((uchar4*)h1f8)[i] = o;
}

// ---------------- edge histogram (deg by dst, 8-way sharded by e&7) ----------------
__global__ void hist_kernel(const int* __restrict__ ei, int* __restrict__ deg8) {
  int i = blockIdx.x * 256 + threadIdx.x;
  if (i < NE) atomicAdd(&deg8[(i & 7) * NN + ei[NE + i]], 1);
}

// ---------------- exclusive scan of deg -> off, sharded cursors ----------------
__global__ void scan_a(const int* __restrict__ deg8, int* __restrict__ bsum,
                       int* __restrict__ degsum) {
  __shared__ int sm[256];
  int t = threadIdx.x, i = blockIdx.x * 256 + t;
  int d = 0;
  if (i < NN) {
#pragma unroll
    for (int j = 0; j < 8; j++) d += deg8[j * NN + i];
    degsum[i] = d;
  }
  sm[t] = d;
  __syncthreads();
  for (int s = 128; s > 0; s >>= 1) {
    if (t < s) sm[t] += sm[t + s];
    __syncthreads();
  }
  if (t == 0) bsum[blockIdx.x] = sm[0];
}
__global__ void scan_b(const int* __restrict__ bsum, int* __restrict__ bscan) {
  __shared__ int sm[256];
  int t = threadIdx.x;
  int own = (t < NB) ? bsum[t] : 0;
  sm[t] = own;
  __syncthreads();
  for (int s = 1; s < 256; s <<= 1) {
    int v = (t >= s) ? sm[t - s] : 0;
    __syncthreads();
    sm[t] += v;
    __syncthreads();
  }
  if (t < NB) bscan[t] = sm[t] - own;  // exclusive over block sums
}
__global__ void scan_c(const int* __restrict__ degsum, const int* __restrict__ deg8,
                       const int* __restrict__ bscan,
                       int* __restrict__ off, int* __restrict__ cursor8) {
  __shared__ int sm[256];
  int t = threadIdx.x, i = blockIdx.x * 256 + t;
  int d = (i < NN) ? degsum[i] : 0;
  sm[t] = d;
  __syncthreads();
  for (int s = 1; s < 256; s <<= 1) {
    int v = (t >= s) ? sm[t - s] : 0;
    __syncthreads();
    sm[t] += v;
    __syncthreads();
  }
  int excl = bscan[blockIdx.x] + sm[t] - d;
  if (i < NN) {
    off[i] = excl;
    int base = excl;
#pragma unroll
    for (int j = 0; j < 8; j++) {
      cursor8[j * NN + i] = base;
      base += deg8[j * NN + i];
    }
    if (i == NN - 1) off[NN] = excl + d;
  }
}

// ---------------- XCD-affine scatter: block (chunk c, xcd x) scatters only ----------
// edges with dst/6250 == x, so each CSR line is written by one XCD only.
// grid = 256 chunks * 8 = 2048 blocks; NE/256 = 3125 edges per chunk.
__global__ void scatter_kernel(const int* __restrict__ ei, int* __restrict__ cursor8,
                               int2* __restrict__ epair) {
  int xcd = blockIdx.x & 7;
  int chunk = blockIdx.x >> 3;
  int lo = chunk * (NE / 256);
  int hi = lo + (NE / 256);
  for (int e = lo + threadIdx.x; e < hi; e += 256) {
    int d = ei[NE + e];
    if (d / (NN / 8) == xcd) {
      int s = ei[e];
      int p = atomicAdd(&cursor8[(e & 7) * NN + d], 1);
      epair[p] = make_int2(s, d);
    }
  }
}

// ---------------- layer1 edge weights + dense esrc, CSR order, coalesced -------------
__global__ void ew1_kernel(const int2* __restrict__ epair,
                           const float* __restrict__ als, const float* __restrict__ ald,
                           float* __restrict__ ew, int* __restrict__ esrc) {
  int k = blockIdx.x * 256 + threadIdx.x;
  if (k >= NE) return;
  int2 e = epair[k];
  esrc[k] = e.x;
  float4 as = *(const float4*)(als + e.x * 4);
  float4 ad = *(const float4*)(ald + e.y * 4);
  float4 w;
  w.x = __expf(lrelu(as.x + ad.x));
  w.y = __expf(lrelu(as.y + ad.y));
  w.z = __expf(lrelu(as.z + ad.z));
  w.w = __expf(lrelu(as.w + ad.w));
  *(float4*)(ew + k * 4) = w;
}

// ---------------- GAT layer1 aggregation: wave/node, fp8, 16 edges/iter --------------
// lane -> edge-group eg=lane>>5 (2 groups), channels c0=(lane&31)*8 (8 ch, head c0>>6).
__global__ __launch_bounds__(256) void agg1_kernel(const unsigned short* __restrict__ h1,
                                                   const unsigned char* __restrict__ h1f8,
                                                   const float* __restrict__ als,
                                                   const float* __restrict__ ald,
                                                   const int* __restrict__ off,
                                                   const int* __restrict__ esrc,
                                                   const float* __restrict__ ew,
                                                   const float* __restrict__ b1,
                                                   unsigned short* __restrict__ out1) {
  int node = blockIdx.x * 4 + (threadIdx.x >> 6);
  int lane = threadIdx.x & 63;
  int eg = lane >> 5;
  int c0 = (lane & 31) * 8;
  int hh = c0 >> 6;
  int beg = off[node], end = off[node + 1];
  float a[8] = {0.f, 0.f, 0.f, 0.f, 0.f, 0.f, 0.f, 0.f};
  float zz = 0.f;
  int k = beg;
  for (; k + 15 < end; k += 16) {
    int idx[8];
    int s[8];
    float w[8];
    uint2 u[8];
#pragma unroll
    for (int j = 0; j < 8; j++) idx[j] = k + 2 * j + eg;
#pragma unroll
    for (int j = 0; j < 8; j++) s[j] = esrc[idx[j]];
#pragma unroll
    for (int j = 0; j < 8; j++) {
      w[j] = ew[idx[j] * 4 + hh];
      u[j] = *(const uint2*)(h1f8 + s[j] * HC + c0);
    }
#pragma unroll
    for (int j = 0; j < 8; j++) {
#pragma unroll
      for (int q = 0; q < 4; q++) {
        a[q] += w[j] * f82f((u[j].x >> (8 * q)) & 0xff);
        a[q + 4] += w[j] * f82f((u[j].y >> (8 * q)) & 0xff);
      }
      zz += w[j];
    }
  }
  for (; k + 7 < end; k += 8) {
    int i0 = k + eg, i1 = k + 2 + eg, i2 = k + 4 + eg, i3 = k + 6 + eg;
    int s0 = esrc[i0], s1 = esrc[i1], s2 = esrc[i2], s3 = esrc[i3];
    float w0 = ew[i0 * 4 + hh], w1 = ew[i1 * 4 + hh];
    float w2 = ew[i2 * 4 + hh], w3 = ew[i3 * 4 + hh];
    uint2 u0 = *(const uint2*)(h1f8 + s0 * HC + c0);
    uint2 u1 = *(const uint2*)(h1f8 + s1 * HC + c0);
    uint2 u2 = *(const uint2*)(h1f8 + s2 * HC + c0);
    uint2 u3 = *(const uint2*)(h1f8 + s3 * HC + c0);
#pragma unroll
    for (int j = 0; j < 4; j++) {
      a[j] += w0 * f82f((u0.x >> (8 * j)) & 0xff) + w1 * f82f((u1.x >> (8 * j)) & 0xff)
            + w2 * f82f((u2.x >> (8 * j)) & 0xff) + w3 * f82f((u3.x >> (8 * j)) & 0xff);
      a[j + 4] += w0 * f82f((u0.y >> (8 * j)) & 0xff) + w1 * f82f((u1.y >> (8 * j)) & 0xff)
                + w2 * f82f((u2.y >> (8 * j)) & 0xff) + w3 * f82f((u3.y >> (8 * j)) & 0xff);
    }
    zz += w0 + w1 + w2 + w3;
  }
  for (; k < end; k += 2) {
    int i0 = k + eg;
    if (i0 < end) {
      int s0 = esrc[i0];
      float w0 = ew[i0 * 4 + hh];
      uint2 u0 = *(const uint2*)(h1f8 + s0 * HC + c0);
#pragma unroll
      for (int j = 0; j < 4; j++) {
        a[j] += w0 * f82f((u0.x >> (8 * j)) & 0xff);
        a[j + 4] += w0 * f82f((u0.y >> (8 * j)) & 0xff);
      }
      zz += w0;
    }
  }
  // combine the two edge-groups (lanes L and L^32 cover the same channels)
#pragma unroll
  for (int j = 0; j < 8; j++) a[j] += __shfl_xor(a[j], 32, 64);
  zz += __shfl_xor(zz, 32, 64);
  if (eg == 0) {
    // self-loop from bf16 original
    float sw = __expf(lrelu(als[node * NHEAD + hh] + ald[node * NHEAD + hh]));
    ushort4 vs0 = *(const ushort4*)(h1 + node * HC + c0);
    ushort4 vs1 = *(const ushort4*)(h1 + node * HC + c0 + 4);
    a[0] += sw * bf2f(vs0.x); a[1] += sw * bf2f(vs0.y);
    a[2] += sw * bf2f(vs0.z); a[3] += sw * bf2f(vs0.w);
    a[4] += sw * bf2f(vs1.x); a[5] += sw * bf2f(vs1.y);
    a[6] += sw * bf2f(vs1.z); a[7] += sw * bf2f(vs1.w);
    zz += sw;
    float inv = 1.f / zz;
    float4 bb0 = *(const float4*)(b1 + c0);
    float4 bb1 = *(const float4*)(b1 + c0 + 4);
    ushort4 o0, o1;
    o0.x = f2bf(a[0] * inv + bb0.x); o0.y = f2bf(a[1] * inv + bb0.y);
    o0.z = f2bf(a[2] * inv + bb0.z); o0.w = f2bf(a[3] * inv + bb0.w);
    o1.x = f2bf(a[4] * inv + bb1.x); o1.y = f2bf(a[5] * inv + bb1.y);
    o1.z = f2bf(a[6] * inv + bb1.z); o1.w = f2bf(a[7] * inv + bb1.w);
    *(ushort4*)(out1 + node * HC + c0) = o0;
    *(ushort4*)(out1 + node * HC + c0 + 4) = o1;
  }
}

// ---------------- BN stats over out1 ----------------
__global__ __launch_bounds__(256) void bnstats_kernel(const unsigned short* __restrict__ out1,
                                                      float* __restrict__ bnsum,
                                                      float* __restrict__ bnsumsq) {
  int t = threadIdx.x;
  float s = 0.f, s2 = 0.f;
  for (int r = blockIdx.x; r < NN; r += gridDim.x) {
    float v = bf2f(out1[r * HC + t]);
    s += v;
    s2 += v * v;
  }
  atomicAdd(&bnsum[t], s);
  atomicAdd(&bnsumsq[t], s2);
}

// ---------------- GEMM2 + fused als2/ald2: h2 = relu(bn(out1)) @ W2 ------------------
__global__ __launch_bounds__(256) void gemm2_kernel(const unsigned short* __restrict__ out1,
                                                    const unsigned short* __restrict__ W2p,
                                                    const float* __restrict__ bnsum,
                                                    const float* __restrict__ bnsumsq,
                                                    const float* __restrict__ gamma,
                                                    const float* __restrict__ beta,
                                                    const float* __restrict__ a_src2,
                                                    const float* __restrict__ a_dst2,
                                                    unsigned short* __restrict__ h2,
                                                    float* __restrict__ als2,
                                                    float* __restrict__ ald2) {
  __shared__ float scale_s[HC], shift_s[HC];
  __shared__ float sh_as[CDIM], sh_ad[CDIM];
  {
    int t = threadIdx.x;
    float mu = bnsum[t] / (float)NN;
    float var = bnsumsq[t] / (float)NN - mu * mu;
    float sc = gamma[t] * rsqrtf(var + 1e-5f);
    scale_s[t] = sc;
    shift_s[t] = beta[t] - mu * sc;
    if (t < CDIM) {
      sh_as[t] = a_src2[t];
      sh_ad[t] = a_dst2[t];
    }
  }
  __syncthreads();
  int wave = threadIdx.x >> 6, lane = threadIdx.x & 63;
  int tile = blockIdx.x * 4 + wave;
  if (tile >= NT1) return;
  int r0 = tile * 16, m = lane & 15, quad = lane >> 4;
  int row = r0 + m;
  short8 a[8];
#pragma unroll
  for (int kk = 0; kk < 8; kk++) {
    int kb = kk * 32 + quad * 8;
    short8 raw = *(const short8*)(out1 + row * HC + kb);
    alignas(16) unsigned short tmp[8];
#pragma unroll
    for (int j = 0; j < 8; j++) {
      tmp[j] = f2bf(relu(bf2f((unsigned short)raw[j]) * scale_s[kb + j] + shift_s[kb + j]));
    }
    a[kk] = *(const short8*)tmp;
  }
  float ps[4] = {0.f, 0.f, 0.f, 0.f};
  float pd[4] = {0.f, 0.f, 0.f, 0.f};
#pragma unroll
  for (int ng = 0; ng < 4; ng++) {
    f32x4 acc = {0.f, 0.f, 0.f, 0.f};
#pragma unroll
    for (int kk = 0; kk < 8; kk++) {
      short8 b = *(const short8*)(W2p + ((ng * 8 + kk) * 64 + lane) * 8);
      acc = __builtin_amdgcn_mfma_f32_16x16x32_bf16(a[kk], b, acc, 0, 0, 0);
    }
    int col = ng * 16 + m;
    float asv = sh_as[col], adv = sh_ad[col];
#pragma unroll
    for (int r = 0; r < 4; r++) {
      h2[(r0 + quad * 4 + r) * CDIM + col] = f2bf(acc[r]);
      ps[r] += acc[r] * asv;
      pd[r] += acc[r] * adv;
    }
  }
#pragma unroll
  for (int o = 1; o < 16; o <<= 1) {
#pragma unroll
    for (int r = 0; r < 4; r++) {
      ps[r] += __shfl_xor(ps[r], o, 64);
      pd[r] += __shfl_xor(pd[r], o, 64);
    }
  }
  if (m == 0) {
#pragma unroll
    for (int r = 0; r < 4; r++) {
      int rr = r0 + quad * 4 + r;
      als2[rr] = ps[r];
      ald2[rr] = pd[r];
    }
  }
}

// ---------------- layer2 edge weights, CSR order, coalesced ----------------
__global__ void ew2_kernel(const int2* __restrict__ epair,
                           const float* __restrict__ als2, const float* __restrict__ ald2,
                           float* __restrict__ ew2) {
  int k = blockIdx.x * 256 + threadIdx.x;
  if (k >= NE) return;
  int2 e = epair[k];
  ew2[k] = __expf(lrelu(als2[e.x] + ald2[e.y]));
}

// ---------------- GAT layer2 agg + ReLU + pooling: wave/node, half-split, 16-deep ----
__global__ __launch_bounds__(256) void agg2_kernel(const unsigned short* __restrict__ h2,
                                                   const float* __restrict__ als2,
                                                   const float* __restrict__ ald2,
                                                   const int* __restrict__ off,
                                                   const int* __restrict__ esrc,
                                                   const float* __restrict__ ew2,
                                                   const float* __restrict__ b2,
                                                   const int* __restrict__ batch,
                                                   float* __restrict__ pooled) {
  int node = blockIdx.x * 4 + (threadIdx.x >> 6);
  int lane = threadIdx.x & 63;
  int half = lane >> 5;
  int cp = (lane & 31) * 2;
  int beg = off[node], end = off[node + 1];
  float a0 = 0.f, a1 = 0.f, zz = 0.f;
  int k = beg;
  for (; k + 15 < end; k += 16) {
    int idx[8];
    int s[8];
    float w[8];
    ushort2 v[8];
#pragma unroll
    for (int j = 0; j < 8; j++) idx[j] = k + 2 * j + half;
#pragma unroll
    for (int j = 0; j < 8; j++) s[j] = esrc[idx[j]];
#pragma unroll
    for (int j = 0; j < 8; j++) {
      w[j] = ew2[idx[j]];
      v[j] = *(const ushort2*)(h2 + s[j] * CDIM + cp);
    }
#pragma unroll
    for (int j = 0; j < 8; j++) {
      a0 += w[j] * bf2f(v[j].x);
      a1 += w[j] * bf2f(v[j].y);
      zz += w[j];
    }
  }
  for (; k + 7 < end; k += 8) {
    int i0 = k + half, i1 = k + 2 + half, i2 = k + 4 + half, i3 = k + 6 + half;
    int s0 = esrc[i0], s1 = esrc[i1], s2 = esrc[i2], s3 = esrc[i3];
    float w0 = ew2[i0], w1 = ew2[i1], w2 = ew2[i2], w3 = ew2[i3];
    ushort2 v0 = *(const ushort2*)(h2 + s0 * CDIM + cp);
    ushort2 v1 = *(const ushort2*)(h2 + s1 * CDIM + cp);
    ushort2 v2 = *(const ushort2*)(h2 + s2 * CDIM + cp);
    ushort2 v3 = *(const ushort2*)(h2 + s3 * CDIM + cp);
    a0 += w0 * bf2f(v0.x) + w1 * bf2f(v1.x) + w2 * bf2f(v2.x) + w3 * bf2f(v3.x);
    a1 += w0 * bf2f(v0.y) + w1 * bf2f(v1.y) + w2 * bf2f(v2.y) + w3 * bf2f(v3.y);
    zz += w0 + w1 + w2 + w3;
  }
  for (; k < end; k += 2) {
    int i0 = k + half;
    if (i0 < end) {
      int s0 = esrc[i0];
      float w0 = ew2[i0];
      ushort2 v0 = *(const ushort2*)(h2 + s0 * CDIM + cp);
      a0 += w0 * bf2f(v0.x);
      a1 += w0 * bf2f(v0.y);
      zz += w0;
    }
  }
  // combine the two halves (lanes L and L^32 cover the same channel pair)
  a0 += __shfl_xor(a0, 32, 64);
  a1 += __shfl_xor(a1, 32, 64);
  zz += __shfl_xor(zz, 32, 64);
  if (half == 0) {
    float sw = __expf(lrelu(als2[node] + ald2[node]));
    ushort2 vs = *(const ushort2*)(h2 + node * CDIM + cp);
    a0 += sw * bf2f(vs.x);
    a1 += sw * bf2f(vs.y);
    zz += sw;
    float inv = 1.f / zz;
    int g = batch[node];
    float v0 = relu(a0 * inv + b2[cp]);
    float v1 = relu(a1 * inv + b2[cp + 1]);
    atomicAdd(&pooled[g * CDIM + cp], v0);
    atomicAdd(&pooled[g * CDIM + cp + 1], v1);
  }
}

// ---------------- pooled mean + classifier (f32 output); counts via binary search ----
__global__ void cls_kernel(const float* __restrict__ pooled, const int* __restrict__ batch,
                           const float* __restrict__ cW1, const float* __restrict__ cb1,
                           const float* __restrict__ cW2, const float* __restrict__ cb2,
                           float* __restrict__ out) {
  __shared__ float p[64];
  __shared__ float z[32];
  int g = blockIdx.x, t = threadIdx.x;
  int lo = 0, hi = NN;
  while (lo < hi) { int mid = (lo + hi) >> 1; if (batch[mid] < g) lo = mid + 1; else hi = mid; }
  int start = lo;
  lo = 0; hi = NN;
  while (lo < hi) { int mid = (lo + hi) >> 1; if (batch[mid] <= g) lo = mid + 1; else hi = mid; }
  int c = lo - start;
  float cnt = (float)(c > 0 ? c : 1);
  p[t] = pooled[g * CDIM + t] / cnt;
  __syncthreads();
  if (t < 32) {
    float a = cb1[t];
    for (int k = 0; k < 64; k++) a += p[k] * cW1[k * 32 + t];
    z[t] = relu(a);
  }
  __syncthreads();
  if (t < NCLS) {
    float a = cb2[t];
    for (int k = 0; k < 32; k++) a += z[k] * cW2[k * NCLS + t];
    out[g * NCLS + t] = a;
  }
}

extern "C" void kernel_launch(void* const* d_in, const int* in_sizes, int n_in,
                              void* d_out, int out_size, void* d_ws, size_t ws_size,
                              hipStream_t stream) {
  const float* x = (const float*)d_in[0];
  const int* edge_index = (const int*)d_in[1];
  const int* batch = (const int*)d_in[2];
  const float* W1 = (const float*)d_in[3];
  const float* a_src1 = (const float*)d_in[4];
  const float* a_dst1 = (const float*)d_in[5];
  const float* b1 = (const float*)d_in[6];
  const float* gamma = (const float*)d_in[7];
  const float* beta = (const float*)d_in[8];
  const float* W2 = (const float*)d_in[9];
  const float* a_src2 = (const float*)d_in[10];
  const float* a_dst2 = (const float*)d_in[11];
  const float* b2 = (const float*)d_in[12];
  const float* cW1 = (const float*)d_in[13];
  const float* cb1 = (const float*)d_in[14];
  const float* cW2 = (const float*)d_in[15];
  const float* cb2 = (const float*)d_in[16];

  // ---- workspace layout ----
  // zero region (contiguous, zeroed every call): deg8 | bnsum | bnsumsq | pooled
  int* deg8 = (int*)d_ws;
  float* bnsum = (float*)(deg8 + 8 * NN);
  float* bnsumsq = bnsum + HC;
  float* pooled = bnsumsq + HC;
  const int ZWORDS = 8 * NN + HC + HC + NGRAPH * CDIM;
  char* p = (char*)(pooled + NGRAPH * CDIM);
  auto align256 = [&](char*& q) {
    size_t a = (size_t)(q - (char*)d_ws);
    a = (a + 255) & ~(size_t)255;
    q = (char*)d_ws + a;
  };
  align256(p);
  int* degsum = (int*)p;          p += (size_t)NN * 4;       align256(p);
  int* offs = (int*)p;            p += (size_t)(NN + 1) * 4; align256(p);
  int* cursor8 = (int*)p;         p += (size_t)8 * NN * 4;   align256(p);
  int2* epair = (int2*)p;         p += (size_t)NE * 8;       align256(p);
  int* esrc = (int*)p;            p += (size_t)NE * 4;       align256(p);
  int* bsum = (int*)p;            p += 256 * 4;              align256(p);
  int* bscan = (int*)p;           p += 256 * 4;              align256(p);
  // h1 region; ew2 (NE*4 = 3.2MB) aliases its head: h1 dead after agg1, ew2 written later
  unsigned short* h1 = (unsigned short*)p;
  float* ew2 = (float*)p;         p += (size_t)NN * HC * 2;   align256(p);
  unsigned short* out1 = (unsigned short*)p; p += (size_t)NN * HC * 2;   align256(p);
  unsigned short* h2 = (unsigned short*)p;   p += (size_t)NN * CDIM * 2; align256(p);
  float* als1 = (float*)p;        p += (size_t)NN * NHEAD * 4; align256(p);
  float* ald1 = (float*)p;        p += (size_t)NN * NHEAD * 4; align256(p);
  float* als2v = (float*)p;       p += (size_t)NN * 4;         align256(p);
  float* ald2v = (float*)p;       p += (size_t)NN * 4;         align256(p);
  float* ew1 = (float*)p;         p += (size_t)NE * NHEAD * 4; align256(p);
  unsigned char* h1f8 = (unsigned char*)p; p += (size_t)NN * HC;        align256(p);
  unsigned short* W1p = (unsigned short*)p; p += 32768 * 2;    align256(p);
  unsigned short* W2p = (unsigned short*)p; p += 16384 * 2;    align256(p);

  zero_kernel<<<(ZWORDS + 255) / 256, 256, 0, stream>>>((int*)d_ws, ZWORDS);
  repack_kernel<<<192, 256, 0, stream>>>(W1, W2, W1p, W2p);
  gemm1_kernel<<<(NT1 + 3) / 4, 256, 0, stream>>>(x, W1p, a_src1, a_dst1, h1, als1, ald1);
  cvt1_kernel<<<NN * HC / 4 / 256, 256, 0, stream>>>(h1, h1f8);
  hist_kernel<<<(NE + 255) / 256, 256, 0, stream>>>(edge_index, deg8);
  scan_a<<<NB, 256, 0, stream>>>(deg8, bsum, degsum);
  scan_b<<<1, 256, 0, stream>>>(bsum, bscan);
  scan_c<<<NB, 256, 0, stream>>>(degsum, deg8, bscan, offs, cursor8);
  scatter_kernel<<<2048, 256, 0, stream>>>(edge_index, cursor8, epair);
  ew1_kernel<<<(NE + 255) / 256, 256, 0, stream>>>(epair, als1, ald1, ew1, esrc);
  agg1_kernel<<<NN / 4, 256, 0, stream>>>(h1, h1f8, als1, ald1, offs, esrc, ew1, b1, out1);
  bnstats_kernel<<<1024, 256, 0, stream>>>(out1, bnsum, bnsumsq);
  gemm2_kernel<<<(NT1 + 3) / 4, 256, 0, stream>>>(out1, W2p, bnsum, bnsumsq, gamma, beta,
                                                  a_src2, a_dst2, h2, als2v, ald2v);
  ew2_kernel<<<(NE + 255) / 256, 256, 0, stream>>>(epair, als2v, ald2v, ew2);
  agg2_kernel<<<NN / 4, 256, 0, stream>>>(h2, als2v, ald2v, offs, esrc, ew2, b2,
                                          batch, pooled);
  cls_kernel<<<NGRAPH, 64, 0, stream>>>(pooled, batch, cW1, cb1, cW2, cb2, (float*)d_out);
}

// Round 15
// 364.106 us; speedup vs baseline: 1.0633x; 1.0044x over previous
//
#include <hip/hip_runtime.h>
#include <hip/hip_bf16.h>
#include <hip/hip_fp8.h>

#define NN 50000
#define NE 800000
#define DIN 128
#define HC 256
#define NHEAD 4
#define CDIM 64
#define NGRAPH 512
#define NCLS 10
#define NEG_SLOPE 0.2f
#define NB 196   // ceil(NN/256)
#define NT1 3125 // NN/16 M-tiles

typedef __hip_bfloat16 bf16;
typedef __attribute__((ext_vector_type(8))) short short8;
typedef __attribute__((ext_vector_type(4))) float f32x4;
typedef __attribute__((ext_vector_type(2))) float f32x2;

__device__ __forceinline__ float bf2f(unsigned short u) {
  union { unsigned int i; float f; } x;
  x.i = ((unsigned int)u) << 16;
  return x.f;
}
__device__ __forceinline__ unsigned short f2bf(float f) {
  bf16 v = __float2bfloat16(f);
  union { bf16 b; unsigned short s; } x;
  x.b = v;
  return x.s;
}
// fp8 e4m3 (OCP) encode/decode via HIP type
__device__ __forceinline__ unsigned char f2f8(float f) {
  __hip_fp8_e4m3 q(f);
  return (unsigned char)q.__x;
}
__device__ __forceinline__ float f82f(unsigned char u) {
  __hip_fp8_e4m3 q;
  q.__x = (__hip_fp8_storage_t)u;
  return (float)q;
}
__device__ __forceinline__ float lrelu(float x) { return x >= 0.f ? x : NEG_SLOPE * x; }
// NaN-propagating relu (fmaxf would silently clamp NaN to 0)
__device__ __forceinline__ float relu(float x) { return x < 0.f ? 0.f : x; }

// ---------------- zero scratch accumulators ----------------
__global__ void zero_kernel(int* __restrict__ p, int n) {
  int i = blockIdx.x * 256 + threadIdx.x;
  if (i < n) p[i] = 0;
}

// ---------------- repack W1,W2 (f32) into MFMA B-frag bf16 order ----------------
__global__ void repack_kernel(const float* __restrict__ W1, const float* __restrict__ W2,
                              unsigned short* __restrict__ W1p, unsigned short* __restrict__ W2p) {
  int i = blockIdx.x * 256 + threadIdx.x;
  if (i < 16 * 4 * 64 * 8) {  // W1: [128,256] -> ng(16) kk(4) lane(64) j(8)
    int j = i & 7, lane = (i >> 3) & 63, kk = (i >> 9) & 3, ng = i >> 11;
    int n = ng * 16 + (lane & 15);
    int k = kk * 32 + (lane >> 4) * 8 + j;
    W1p[i] = f2bf(W1[k * HC + n]);
  }
  int i2 = i - 16 * 4 * 64 * 8;
  if (i2 >= 0 && i2 < 4 * 8 * 64 * 8) {  // W2: [256,64] -> ng(4) kk(8) lane(64) j(8)
    int j = i2 & 7, lane = (i2 >> 3) & 63, kk = (i2 >> 9) & 7, ng = i2 >> 12;
    int n = ng * 16 + (lane & 15);
    int k = kk * 32 + (lane >> 4) * 8 + j;
    W2p[i2] = f2bf(W2[k * CDIM + n]);
  }
}

// ---------------- GEMM1 + fused als1/ald1: h1 = bf16(x) @ W1  (bf16 MFMA) ------------
__global__ __launch_bounds__(256) void gemm1_kernel(const float* __restrict__ x,
                                                    const unsigned short* __restrict__ W1p,
                                                    const float* __restrict__ a_src,
                                                    const float* __restrict__ a_dst,
                                                    unsigned short* __restrict__ h1,
                                                    float* __restrict__ als,
                                                    float* __restrict__ ald) {
  __shared__ float sh_as[HC], sh_ad[HC];
  {
    int t = threadIdx.x;
    sh_as[t] = a_src[t];
    sh_ad[t] = a_dst[t];
  }
  __syncthreads();
  int wave = threadIdx.x >> 6, lane = threadIdx.x & 63;
  int tile = blockIdx.x * 4 + wave;
  if (tile >= NT1) return;
  int r0 = tile * 16, m = lane & 15, quad = lane >> 4;
  int row = r0 + m;
  short8 a[4];
#pragma unroll
  for (int kk = 0; kk < 4; kk++) {
    int kb = kk * 32 + quad * 8;
    float4 f0 = *(const float4*)(x + row * DIN + kb);
    float4 f1 = *(const float4*)(x + row * DIN + kb + 4);
    alignas(16) unsigned short tmp[8];
    tmp[0] = f2bf(f0.x); tmp[1] = f2bf(f0.y); tmp[2] = f2bf(f0.z); tmp[3] = f2bf(f0.w);
    tmp[4] = f2bf(f1.x); tmp[5] = f2bf(f1.y); tmp[6] = f2bf(f1.z); tmp[7] = f2bf(f1.w);
    a[kk] = *(const short8*)tmp;
  }
#pragma unroll
  for (int hg = 0; hg < 4; hg++) {
    float ps[4] = {0.f, 0.f, 0.f, 0.f};
    float pd[4] = {0.f, 0.f, 0.f, 0.f};
#pragma unroll
    for (int sub = 0; sub < 4; sub++) {
      int ng = hg * 4 + sub;
      f32x4 acc = {0.f, 0.f, 0.f, 0.f};
#pragma unroll
      for (int kk = 0; kk < 4; kk++) {
        short8 b = *(const short8*)(W1p + ((ng * 4 + kk) * 64 + lane) * 8);
        acc = __builtin_amdgcn_mfma_f32_16x16x32_bf16(a[kk], b, acc, 0, 0, 0);
      }
      int col = ng * 16 + m;
      float asv = sh_as[col], adv = sh_ad[col];
#pragma unroll
      for (int r = 0; r < 4; r++) {
        h1[(r0 + quad * 4 + r) * HC + col] = f2bf(acc[r]);
        ps[r] += acc[r] * asv;
        pd[r] += acc[r] * adv;
      }
    }
#pragma unroll
    for (int o = 1; o < 16; o <<= 1) {
#pragma unroll
      for (int r = 0; r < 4; r++) {
        ps[r] += __shfl_xor(ps[r], o, 64);
        pd[r] += __shfl_xor(pd[r], o, 64);
      }
    }
    if (m == 0) {
#pragma unroll
      for (int r = 0; r < 4; r++) {
        int rr = r0 + quad * 4 + r;
        als[rr * NHEAD + hg] = ps[r];
        ald[rr * NHEAD + hg] = pd[r];
      }
    }
  }
}

// ---------------- bf16 -> fp8 shadow copy of h1 for the gather path ----------------
__global__ void cvt1_kernel(const unsigned short* __restrict__ h1,
                            unsigned char* __restrict__ h1f8) {
  int i = blockIdx.x * 256 + threadIdx.x;  // i < NN*HC/4
  ushort4 v = ((const ushort4*)h1)[i];
  uchar4 o;
  o.x = f2f8(bf2f(v.x));
  o.y = f2f8(bf2f(v.y));
  o.z = f2f8(bf2f(v.z));
  o.w = f2f8(bf2f(v.w));
  ((uchar4*)h1f8)[i] = o;
}

// ---------------- edge histogram (deg by dst, 8-way sharded by e&7) ----------------
__global__ void hist_kernel(const int* __restrict__ ei, int* __restrict__ deg8) {
  int i = blockIdx.x * 256 + threadIdx.x;
  if (i < NE) atomicAdd(&deg8[(i & 7) * NN + ei[NE + i]], 1);
}

// ---------------- exclusive scan of deg -> off, sharded cursors ----------------
__global__ void scan_a(const int* __restrict__ deg8, int* __restrict__ bsum,
                       int* __restrict__ degsum) {
  __shared__ int sm[256];
  int t = threadIdx.x, i = blockIdx.x * 256 + t;
  int d = 0;
  if (i < NN) {
#pragma unroll
    for (int j = 0; j < 8; j++) d += deg8[j * NN + i];
    degsum[i] = d;
  }
  sm[t] = d;
  __syncthreads();
  for (int s = 128; s > 0; s >>= 1) {
    if (t < s) sm[t] += sm[t + s];
    __syncthreads();
  }
  if (t == 0) bsum[blockIdx.x] = sm[0];
}
__global__ void scan_b(const int* __restrict__ bsum, int* __restrict__ bscan) {
  __shared__ int sm[256];
  int t = threadIdx.x;
  int own = (t < NB) ? bsum[t] : 0;
  sm[t] = own;
  __syncthreads();
  for (int s = 1; s < 256; s <<= 1) {
    int v = (t >= s) ? sm[t - s] : 0;
    __syncthreads();
    sm[t] += v;
    __syncthreads();
  }
  if (t < NB) bscan[t] = sm[t] - own;  // exclusive over block sums
}
__global__ void scan_c(const int* __restrict__ degsum, const int* __restrict__ deg8,
                       const int* __restrict__ bscan,
                       int* __restrict__ off, int* __restrict__ cursor8) {
  __shared__ int sm[256];
  int t = threadIdx.x, i = blockIdx.x * 256 + t;
  int d = (i < NN) ? degsum[i] : 0;
  sm[t] = d;
  __syncthreads();
  for (int s = 1; s < 256; s <<= 1) {
    int v = (t >= s) ? sm[t - s] : 0;
    __syncthreads();
    sm[t] += v;
    __syncthreads();
  }
  int excl = bscan[blockIdx.x] + sm[t] - d;
  if (i < NN) {
    off[i] = excl;
    int base = excl;
#pragma unroll
    for (int j = 0; j < 8; j++) {
      cursor8[j * NN + i] = base;
      base += deg8[j * NN + i];
    }
    if (i == NN - 1) off[NN] = excl + d;
  }
}

// ---------------- XCD-affine scatter: block (chunk c, xcd x) scatters only ----------
// edges with dst/6250 == x, so each CSR line is written by one XCD only.
// grid = 256 chunks * 8 = 2048 blocks; NE/256 = 3125 edges per chunk.
__global__ void scatter_kernel(const int* __restrict__ ei, int* __restrict__ cursor8,
                               int2* __restrict__ epair) {
  int xcd = blockIdx.x & 7;
  int chunk = blockIdx.x >> 3;
  int lo = chunk * (NE / 256);
  int hi = lo + (NE / 256);
  for (int e = lo + threadIdx.x; e < hi; e += 256) {
    int d = ei[NE + e];
    if (d / (NN / 8) == xcd) {
      int s = ei[e];
      int p = atomicAdd(&cursor8[(e & 7) * NN + d], 1);
      epair[p] = make_int2(s, d);
    }
  }
}

// ---------------- layer1 edge weights + dense esrc, CSR order, coalesced -------------
__global__ void ew1_kernel(const int2* __restrict__ epair,
                           const float* __restrict__ als, const float* __restrict__ ald,
                           float* __restrict__ ew, int* __restrict__ esrc) {
  int k = blockIdx.x * 256 + threadIdx.x;
  if (k >= NE) return;
  int2 e = epair[k];
  esrc[k] = e.x;
  float4 as = *(const float4*)(als + e.x * 4);
  float4 ad = *(const float4*)(ald + e.y * 4);
  float4 w;
  w.x = __expf(lrelu(as.x + ad.x));
  w.y = __expf(lrelu(as.y + ad.y));
  w.z = __expf(lrelu(as.z + ad.z));
  w.w = __expf(lrelu(as.w + ad.w));
  *(float4*)(ew + k * 4) = w;
}

// ---------------- GAT layer1 aggregation: wave/node, fp8 HW-packed decode ------------
// lane -> edge-group eg=lane>>5 (2 groups), channels c0=(lane&31)*8 (8 ch, head c0>>6).
__global__ __launch_bounds__(256) void agg1_kernel(const unsigned short* __restrict__ h1,
                                                   const unsigned char* __restrict__ h1f8,
                                                   const float* __restrict__ als,
                                                   const float* __restrict__ ald,
                                                   const int* __restrict__ off,
                                                   const int* __restrict__ esrc,
                                                   const float* __restrict__ ew,
                                                   const float* __restrict__ b1,
                                                   unsigned short* __restrict__ out1) {
  int node = blockIdx.x * 4 + (threadIdx.x >> 6);
  int lane = threadIdx.x & 63;
  int eg = lane >> 5;
  int c0 = (lane & 31) * 8;
  int hh = c0 >> 6;
  int beg = off[node], end = off[node + 1];
  float a[8] = {0.f, 0.f, 0.f, 0.f, 0.f, 0.f, 0.f, 0.f};
  float zz = 0.f;
  int k = beg;
  for (; k + 15 < end; k += 16) {
    int idx[8];
    int s[8];
    float w[8];
    uint2 u[8];
#pragma unroll
    for (int j = 0; j < 8; j++) idx[j] = k + 2 * j + eg;
#pragma unroll
    for (int j = 0; j < 8; j++) s[j] = esrc[idx[j]];
#pragma unroll
    for (int j = 0; j < 8; j++) {
      w[j] = ew[idx[j] * 4 + hh];
      u[j] = *(const uint2*)(h1f8 + s[j] * HC + c0);
    }
#pragma unroll
    for (int j = 0; j < 8; j++) {
      f32x2 p0 = __builtin_amdgcn_cvt_pk_f32_fp8(u[j].x, false);
      f32x2 p1 = __builtin_amdgcn_cvt_pk_f32_fp8(u[j].x, true);
      f32x2 p2 = __builtin_amdgcn_cvt_pk_f32_fp8(u[j].y, false);
      f32x2 p3 = __builtin_amdgcn_cvt_pk_f32_fp8(u[j].y, true);
      a[0] += w[j] * p0.x; a[1] += w[j] * p0.y;
      a[2] += w[j] * p1.x; a[3] += w[j] * p1.y;
      a[4] += w[j] * p2.x; a[5] += w[j] * p2.y;
      a[6] += w[j] * p3.x; a[7] += w[j] * p3.y;
      zz += w[j];
    }
  }
  for (; k + 7 < end; k += 8) {
    int i0 = k + eg, i1 = k + 2 + eg, i2 = k + 4 + eg, i3 = k + 6 + eg;
    int s0 = esrc[i0], s1 = esrc[i1], s2 = esrc[i2], s3 = esrc[i3];
    float w0 = ew[i0 * 4 + hh], w1 = ew[i1 * 4 + hh];
    float w2 = ew[i2 * 4 + hh], w3 = ew[i3 * 4 + hh];
    uint2 u0 = *(const uint2*)(h1f8 + s0 * HC + c0);
    uint2 u1 = *(const uint2*)(h1f8 + s1 * HC + c0);
    uint2 u2 = *(const uint2*)(h1f8 + s2 * HC + c0);
    uint2 u3 = *(const uint2*)(h1f8 + s3 * HC + c0);
    {
      f32x2 p0 = __builtin_amdgcn_cvt_pk_f32_fp8(u0.x, false);
      f32x2 p1 = __builtin_amdgcn_cvt_pk_f32_fp8(u0.x, true);
      f32x2 p2 = __builtin_amdgcn_cvt_pk_f32_fp8(u0.y, false);
      f32x2 p3 = __builtin_amdgcn_cvt_pk_f32_fp8(u0.y, true);
      a[0] += w0 * p0.x; a[1] += w0 * p0.y; a[2] += w0 * p1.x; a[3] += w0 * p1.y;
      a[4] += w0 * p2.x; a[5] += w0 * p2.y; a[6] += w0 * p3.x; a[7] += w0 * p3.y;
    }
    {
      f32x2 p0 = __builtin_amdgcn_cvt_pk_f32_fp8(u1.x, false);
      f32x2 p1 = __builtin_amdgcn_cvt_pk_f32_fp8(u1.x, true);
      f32x2 p2 = __builtin_amdgcn_cvt_pk_f32_fp8(u1.y, false);
      f32x2 p3 = __builtin_amdgcn_cvt_pk_f32_fp8(u1.y, true);
      a[0] += w1 * p0.x; a[1] += w1 * p0.y; a[2] += w1 * p1.x; a[3] += w1 * p1.y;
      a[4] += w1 * p2.x; a[5] += w1 * p2.y; a[6] += w1 * p3.x; a[7] += w1 * p3.y;
    }
    {
      f32x2 p0 = __builtin_amdgcn_cvt_pk_f32_fp8(u2.x, false);
      f32x2 p1 = __builtin_amdgcn_cvt_pk_f32_fp8(u2.x, true);
      f32x2 p2 = __builtin_amdgcn_cvt_pk_f32_fp8(u2.y, false);
      f32x2 p3 = __builtin_amdgcn_cvt_pk_f32_fp8(u2.y, true);
      a[0] += w2 * p0.x; a[1] += w2 * p0.y; a[2] += w2 * p1.x; a[3] += w2 * p1.y;
      a[4] += w2 * p2.x; a[5] += w2 * p2.y; a[6] += w2 * p3.x; a[7] += w2 * p3.y;
    }
    {
      f32x2 p0 = __builtin_amdgcn_cvt_pk_f32_fp8(u3.x, false);
      f32x2 p1 = __builtin_amdgcn_cvt_pk_f32_fp8(u3.x, true);
      f32x2 p2 = __builtin_amdgcn_cvt_pk_f32_fp8(u3.y, false);
      f32x2 p3 = __builtin_amdgcn_cvt_pk_f32_fp8(u3.y, true);
      a[0] += w3 * p0.x; a[1] += w3 * p0.y; a[2] += w3 * p1.x; a[3] += w3 * p1.y;
      a[4] += w3 * p2.x; a[5] += w3 * p2.y; a[6] += w3 * p3.x; a[7] += w3 * p3.y;
    }
    zz += w0 + w1 + w2 + w3;
  }
  for (; k < end; k += 2) {
    int i0 = k + eg;
    if (i0 < end) {
      int s0 = esrc[i0];
      float w0 = ew[i0 * 4 + hh];
      uint2 u0 = *(const uint2*)(h1f8 + s0 * HC + c0);
      f32x2 p0 = __builtin_amdgcn_cvt_pk_f32_fp8(u0.x, false);
      f32x2 p1 = __builtin_amdgcn_cvt_pk_f32_fp8(u0.x, true);
      f32x2 p2 = __builtin_amdgcn_cvt_pk_f32_fp8(u0.y, false);
      f32x2 p3 = __builtin_amdgcn_cvt_pk_f32_fp8(u0.y, true);
      a[0] += w0 * p0.x; a[1] += w0 * p0.y; a[2] += w0 * p1.x; a[3] += w0 * p1.y;
      a[4] += w0 * p2.x; a[5] += w0 * p2.y; a[6] += w0 * p3.x; a[7] += w0 * p3.y;
      zz += w0;
    }
  }
  // combine the two edge-groups (lanes L and L^32 cover the same channels)
#pragma unroll
  for (int j = 0; j < 8; j++) a[j] += __shfl_xor(a[j], 32, 64);
  zz += __shfl_xor(zz, 32, 64);
  if (eg == 0) {
    // self-loop from bf16 original
    float sw = __expf(lrelu(als[node * NHEAD + hh] + ald[node * NHEAD + hh]));
    ushort4 vs0 = *(const ushort4*)(h1 + node * HC + c0);
    ushort4 vs1 = *(const ushort4*)(h1 + node * HC + c0 + 4);
    a[0] += sw * bf2f(vs0.x); a[1] += sw * bf2f(vs0.y);
    a[2] += sw * bf2f(vs0.z); a[3] += sw * bf2f(vs0.w);
    a[4] += sw * bf2f(vs1.x); a[5] += sw * bf2f(vs1.y);
    a[6] += sw * bf2f(vs1.z); a[7] += sw * bf2f(vs1.w);
    zz += sw;
    float inv = 1.f / zz;
    float4 bb0 = *(const float4*)(b1 + c0);
    float4 bb1 = *(const float4*)(b1 + c0 + 4);
    ushort4 o0, o1;
    o0.x = f2bf(a[0] * inv + bb0.x); o0.y = f2bf(a[1] * inv + bb0.y);
    o0.z = f2bf(a[2] * inv + bb0.z); o0.w = f2bf(a[3] * inv + bb0.w);
    o1.x = f2bf(a[4] * inv + bb1.x); o1.y = f2bf(a[5] * inv + bb1.y);
    o1.z = f2bf(a[6] * inv + bb1.z); o1.w = f2bf(a[7] * inv + bb1.w);
    *(ushort4*)(out1 + node * HC + c0) = o0;
    *(ushort4*)(out1 + node * HC + c0 + 4) = o1;
  }
}

// ---------------- BN stats over out1 ----------------
__global__ __launch_bounds__(256) void bnstats_kernel(const unsigned short* __restrict__ out1,
                                                      float* __restrict__ bnsum,
                                                      float* __restrict__ bnsumsq) {
  int t = threadIdx.x;
  float s = 0.f, s2 = 0.f;
  for (int r = blockIdx.x; r < NN; r += gridDim.x) {
    float v = bf2f(out1[r * HC + t]);
    s += v;
    s2 += v * v;
  }
  atomicAdd(&bnsum[t], s);
  atomicAdd(&bnsumsq[t], s2);
}

// ---------------- GEMM2 + fused als2/ald2: h2 = relu(bn(out1)) @ W2 ------------------
__global__ __launch_bounds__(256) void gemm2_kernel(const unsigned short* __restrict__ out1,
                                                    const unsigned short* __restrict__ W2p,
                                                    const float* __restrict__ bnsum,
                                                    const float* __restrict__ bnsumsq,
                                                    const float* __restrict__ gamma,
                                                    const float* __restrict__ beta,
                                                    const float* __restrict__ a_src2,
                                                    const float* __restrict__ a_dst2,
                                                    unsigned short* __restrict__ h2,
                                                    float* __restrict__ als2,
                                                    float* __restrict__ ald2) {
  __shared__ float scale_s[HC], shift_s[HC];
  __shared__ float sh_as[CDIM], sh_ad[CDIM];
  {
    int t = threadIdx.x;
    float mu = bnsum[t] / (float)NN;
    float var = bnsumsq[t] / (float)NN - mu * mu;
    float sc = gamma[t] * rsqrtf(var + 1e-5f);
    scale_s[t] = sc;
    shift_s[t] = beta[t] - mu * sc;
    if (t < CDIM) {
      sh_as[t] = a_src2[t];
      sh_ad[t] = a_dst2[t];
    }
  }
  __syncthreads();
  int wave = threadIdx.x >> 6, lane = threadIdx.x & 63;
  int tile = blockIdx.x * 4 + wave;
  if (tile >= NT1) return;
  int r0 = tile * 16, m = lane & 15, quad = lane >> 4;
  int row = r0 + m;
  short8 a[8];
#pragma unroll
  for (int kk = 0; kk < 8; kk++) {
    int kb = kk * 32 + quad * 8;
    short8 raw = *(const short8*)(out1 + row * HC + kb);
    alignas(16) unsigned short tmp[8];
#pragma unroll
    for (int j = 0; j < 8; j++) {
      tmp[j] = f2bf(relu(bf2f((unsigned short)raw[j]) * scale_s[kb + j] + shift_s[kb + j]));
    }
    a[kk] = *(const short8*)tmp;
  }
  float ps[4] = {0.f, 0.f, 0.f, 0.f};
  float pd[4] = {0.f, 0.f, 0.f, 0.f};
#pragma unroll
  for (int ng = 0; ng < 4; ng++) {
    f32x4 acc = {0.f, 0.f, 0.f, 0.f};
#pragma unroll
    for (int kk = 0; kk < 8; kk++) {
      short8 b = *(const short8*)(W2p + ((ng * 8 + kk) * 64 + lane) * 8);
      acc = __builtin_amdgcn_mfma_f32_16x16x32_bf16(a[kk], b, acc, 0, 0, 0);
    }
    int col = ng * 16 + m;
    float asv = sh_as[col], adv = sh_ad[col];
#pragma unroll
    for (int r = 0; r < 4; r++) {
      h2[(r0 + quad * 4 + r) * CDIM + col] = f2bf(acc[r]);
      ps[r] += acc[r] * asv;
      pd[r] += acc[r] * adv;
    }
  }
#pragma unroll
  for (int o = 1; o < 16; o <<= 1) {
#pragma unroll
    for (int r = 0; r < 4; r++) {
      ps[r] += __shfl_xor(ps[r], o, 64);
      pd[r] += __shfl_xor(pd[r], o, 64);
    }
  }
  if (m == 0) {
#pragma unroll
    for (int r = 0; r < 4; r++) {
      int rr = r0 + quad * 4 + r;
      als2[rr] = ps[r];
      ald2[rr] = pd[r];
    }
  }
}

// ---------------- layer2 edge weights, CSR order, coalesced ----------------
__global__ void ew2_kernel(const int2* __restrict__ epair,
                           const float* __restrict__ als2, const float* __restrict__ ald2,
                           float* __restrict__ ew2) {
  int k = blockIdx.x * 256 + threadIdx.x;
  if (k >= NE) return;
  int2 e = epair[k];
  ew2[k] = __expf(lrelu(als2[e.x] + ald2[e.y]));
}

// ---------------- GAT layer2 agg + ReLU + pooling: wave/node, half-split, 16-deep ----
__global__ __launch_bounds__(256) void agg2_kernel(const unsigned short* __restrict__ h2,
                                                   const float* __restrict__ als2,
                                                   const float* __restrict__ ald2,
                                                   const int* __restrict__ off,
                                                   const int* __restrict__ esrc,
                                                   const float* __restrict__ ew2,
                                                   const float* __restrict__ b2,
                                                   const int* __restrict__ batch,
                                                   float* __restrict__ pooled) {
  int node = blockIdx.x * 4 + (threadIdx.x >> 6);
  int lane = threadIdx.x & 63;
  int half = lane >> 5;
  int cp = (lane & 31) * 2;
  int beg = off[node], end = off[node + 1];
  float a0 = 0.f, a1 = 0.f, zz = 0.f;
  int k = beg;
  for (; k + 15 < end; k += 16) {
    int idx[8];
    int s[8];
    float w[8];
    ushort2 v[8];
#pragma unroll
    for (int j = 0; j < 8; j++) idx[j] = k + 2 * j + half;
#pragma unroll
    for (int j = 0; j < 8; j++) s[j] = esrc[idx[j]];
#pragma unroll
    for (int j = 0; j < 8; j++) {
      w[j] = ew2[idx[j]];
      v[j] = *(const ushort2*)(h2 + s[j] * CDIM + cp);
    }
#pragma unroll
    for (int j = 0; j < 8; j++) {
      a0 += w[j] * bf2f(v[j].x);
      a1 += w[j] * bf2f(v[j].y);
      zz += w[j];
    }
  }
  for (; k + 7 < end; k += 8) {
    int i0 = k + half, i1 = k + 2 + half, i2 = k + 4 + half, i3 = k + 6 + half;
    int s0 = esrc[i0], s1 = esrc[i1], s2 = esrc[i2], s3 = esrc[i3];
    float w0 = ew2[i0], w1 = ew2[i1], w2 = ew2[i2], w3 = ew2[i3];
    ushort2 v0 = *(const ushort2*)(h2 + s0 * CDIM + cp);
    ushort2 v1 = *(const ushort2*)(h2 + s1 * CDIM + cp);
    ushort2 v2 = *(const ushort2*)(h2 + s2 * CDIM + cp);
    ushort2 v3 = *(const ushort2*)(h2 + s3 * CDIM + cp);
    a0 += w0 * bf2f(v0.x) + w1 * bf2f(v1.x) + w2 * bf2f(v2.x) + w3 * bf2f(v3.x);
    a1 += w0 * bf2f(v0.y) + w1 * bf2f(v1.y) + w2 * bf2f(v2.y) + w3 * bf2f(v3.y);
    zz += w0 + w1 + w2 + w3;
  }
  for (; k < end; k += 2) {
    int i0 = k + half;
    if (i0 < end) {
      int s0 = esrc[i0];
      float w0 = ew2[i0];
      ushort2 v0 = *(const ushort2*)(h2 + s0 * CDIM + cp);
      a0 += w0 * bf2f(v0.x);
      a1 += w0 * bf2f(v0.y);
      zz += w0;
    }
  }
  // combine the two halves (lanes L and L^32 cover the same channel pair)
  a0 += __shfl_xor(a0, 32, 64);
  a1 += __shfl_xor(a1, 32, 64);
  zz += __shfl_xor(zz, 32, 64);
  if (half == 0) {
    float sw = __expf(lrelu(als2[node] + ald2[node]));
    ushort2 vs = *(const ushort2*)(h2 + node * CDIM + cp);
    a0 += sw * bf2f(vs.x);
    a1 += sw * bf2f(vs.y);
    zz += sw;
    float inv = 1.f / zz;
    int g = batch[node];
    float v0 = relu(a0 * inv + b2[cp]);
    float v1 = relu(a1 * inv + b2[cp + 1]);
    atomicAdd(&pooled[g * CDIM + cp], v0);
    atomicAdd(&pooled[g * CDIM + cp + 1], v1);
  }
}

// ---------------- pooled mean + classifier (f32 output); counts via binary search ----
__global__ void cls_kernel(const float* __restrict__ pooled, const int* __restrict__ batch,
                           const float* __restrict__ cW1, const float* __restrict__ cb1,
                           const float* __restrict__ cW2, const float* __restrict__ cb2,
                           float* __restrict__ out) {
  __shared__ float p[64];
  __shared__ float z[32];
  int g = blockIdx.x, t = threadIdx.x;
  int lo = 0, hi = NN;
  while (lo < hi) { int mid = (lo + hi) >> 1; if (batch[mid] < g) lo = mid + 1; else hi = mid; }
  int start = lo;
  lo = 0; hi = NN;
  while (lo < hi) { int mid = (lo + hi) >> 1; if (batch[mid] <= g) lo = mid + 1; else hi = mid; }
  int c = lo - start;
  float cnt = (float)(c > 0 ? c : 1);
  p[t] = pooled[g * CDIM + t] / cnt;
  __syncthreads();
  if (t < 32) {
    float a = cb1[t];
    for (int k = 0; k < 64; k++) a += p[k] * cW1[k * 32 + t];
    z[t] = relu(a);
  }
  __syncthreads();
  if (t < NCLS) {
    float a = cb2[t];
    for (int k = 0; k < 32; k++) a += z[k] * cW2[k * NCLS + t];
    out[g * NCLS + t] = a;
  }
}

extern "C" void kernel_launch(void* const* d_in, const int* in_sizes, int n_in,
                              void* d_out, int out_size, void* d_ws, size_t ws_size,
                              hipStream_t stream) {
  const float* x = (const float*)d_in[0];
  const int* edge_index = (const int*)d_in[1];
  const int* batch = (const int*)d_in[2];
  const float* W1 = (const float*)d_in[3];
  const float* a_src1 = (const float*)d_in[4];
  const float* a_dst1 = (const float*)d_in[5];
  const float* b1 = (const float*)d_in[6];
  const float* gamma = (const float*)d_in[7];
  const float* beta = (const float*)d_in[8];
  const float* W2 = (const float*)d_in[9];
  const float* a_src2 = (const float*)d_in[10];
  const float* a_dst2 = (const float*)d_in[11];
  const float* b2 = (const float*)d_in[12];
  const float* cW1 = (const float*)d_in[13];
  const float* cb1 = (const float*)d_in[14];
  const float* cW2 = (const float*)d_in[15];
  const float* cb2 = (const float*)d_in[16];

  // ---- workspace layout ----
  // zero region (contiguous, zeroed every call): deg8 | bnsum | bnsumsq | pooled
  int* deg8 = (int*)d_ws;
  float* bnsum = (float*)(deg8 + 8 * NN);
  float* bnsumsq = bnsum + HC;
  float* pooled = bnsumsq + HC;
  const int ZWORDS = 8 * NN + HC + HC + NGRAPH * CDIM;
  char* p = (char*)(pooled + NGRAPH * CDIM);
  auto align256 = [&](char*& q) {
    size_t a = (size_t)(q - (char*)d_ws);
    a = (a + 255) & ~(size_t)255;
    q = (char*)d_ws + a;
  };
  align256(p);
  int* degsum = (int*)p;          p += (size_t)NN * 4;       align256(p);
  int* offs = (int*)p;            p += (size_t)(NN + 1) * 4; align256(p);
  int* cursor8 = (int*)p;         p += (size_t)8 * NN * 4;   align256(p);
  int2* epair = (int2*)p;         p += (size_t)NE * 8;       align256(p);
  int* esrc = (int*)p;            p += (size_t)NE * 4;       align256(p);
  int* bsum = (int*)p;            p += 256 * 4;              align256(p);
  int* bscan = (int*)p;           p += 256 * 4;              align256(p);
  // h1 region; ew2 (NE*4 = 3.2MB) aliases its head: h1 dead after agg1, ew2 written later
  unsigned short* h1 = (unsigned short*)p;
  float* ew2 = (float*)p;         p += (size_t)NN * HC * 2;   align256(p);
  unsigned short* out1 = (unsigned short*)p; p += (size_t)NN * HC * 2;   align256(p);
  unsigned short* h2 = (unsigned short*)p;   p += (size_t)NN * CDIM * 2; align256(p);
  float* als1 = (float*)p;        p += (size_t)NN * NHEAD * 4; align256(p);
  float* ald1 = (float*)p;        p += (size_t)NN * NHEAD * 4; align256(p);
  float* als2v = (float*)p;       p += (size_t)NN * 4;         align256(p);
  float* ald2v = (float*)p;       p += (size_t)NN * 4;         align256(p);
  float* ew1 = (float*)p;         p += (size_t)NE * NHEAD * 4; align256(p);
  unsigned char* h1f8 = (unsigned char*)p; p += (size_t)NN * HC;        align256(p);
  unsigned short* W1p = (unsigned short*)p; p += 32768 * 2;    align256(p);
  unsigned short* W2p = (unsigned short*)p; p += 16384 * 2;    align256(p);

  zero_kernel<<<(ZWORDS + 255) / 256, 256, 0, stream>>>((int*)d_ws, ZWORDS);
  repack_kernel<<<192, 256, 0, stream>>>(W1, W2, W1p, W2p);
  gemm1_kernel<<<(NT1 + 3) / 4, 256, 0, stream>>>(x, W1p, a_src1, a_dst1, h1, als1, ald1);
  cvt1_kernel<<<NN * HC / 4 / 256, 256, 0, stream>>>(h1, h1f8);
  hist_kernel<<<(NE + 255) / 256, 256, 0, stream>>>(edge_index, deg8);
  scan_a<<<NB, 256, 0, stream>>>(deg8, bsum, degsum);
  scan_b<<<1, 256, 0, stream>>>(bsum, bscan);
  scan_c<<<NB, 256, 0, stream>>>(degsum, deg8, bscan, offs, cursor8);
  scatter_kernel<<<2048, 256, 0, stream>>>(edge_index, cursor8, epair);
  ew1_kernel<<<(NE + 255) / 256, 256, 0, stream>>>(epair, als1, ald1, ew1, esrc);
  agg1_kernel<<<NN / 4, 256, 0, stream>>>(h1, h1f8, als1, ald1, offs, esrc, ew1, b1, out1);
  bnstats_kernel<<<1024, 256, 0, stream>>>(out1, bnsum, bnsumsq);
  gemm2_kernel<<<(NT1 + 3) / 4, 256, 0, stream>>>(out1, W2p, bnsum, bnsumsq, gamma, beta,
                                                  a_src2, a_dst2, h2, als2v, ald2v);
  ew2_kernel<<<(NE + 255) / 256, 256, 0, stream>>>(epair, als2v, ald2v, ew2);
  agg2_kernel<<<NN / 4, 256, 0, stream>>>(h2, als2v, ald2v, offs, esrc, ew2, b2,
                                          batch, pooled);
  cls_kernel<<<NGRAPH, 64, 0, stream>>>(pooled, batch, cW1, cb1, cW2, cb2, (float*)d_out);
}

// Round 16
// 348.733 us; speedup vs baseline: 1.1101x; 1.0441x over previous
//
#include <hip/hip_runtime.h>
#include <hip/hip_bf16.h>
#include <hip/hip_fp8.h>

#define NN 50000
#define NE 800000
#define DIN 128
#define HC 256
#define NHEAD 4
#define CDIM 64
#define NGRAPH 512
#define NCLS 10
#define NEG_SLOPE 0.2f
#define NB 196   // ceil(NN/256)
#define NT1 3125 // NN/16 M-tiles

typedef __hip_bfloat16 bf16;
typedef __attribute__((ext_vector_type(8))) short short8;
typedef __attribute__((ext_vector_type(4))) float f32x4;
typedef __attribute__((ext_vector_type(2))) float f32x2;

__device__ __forceinline__ float bf2f(unsigned short u) {
  union { unsigned int i; float f; } x;
  x.i = ((unsigned int)u) << 16;
  return x.f;
}
__device__ __forceinline__ unsigned short f2bf(float f) {
  bf16 v = __float2bfloat16(f);
  union { bf16 b; unsigned short s; } x;
  x.b = v;
  return x.s;
}
// fp8 e4m3 (OCP) encode/decode via HIP type
__device__ __forceinline__ unsigned char f2f8(float f) {
  __hip_fp8_e4m3 q(f);
  return (unsigned char)q.__x;
}
__device__ __forceinline__ float lrelu(float x) { return x >= 0.f ? x : NEG_SLOPE * x; }
// NaN-propagating relu (fmaxf would silently clamp NaN to 0)
__device__ __forceinline__ float relu(float x) { return x < 0.f ? 0.f : x; }

// ---------------- zero scratch accumulators ----------------
__global__ void zero_kernel(int* __restrict__ p, int n) {
  int i = blockIdx.x * 256 + threadIdx.x;
  if (i < n) p[i] = 0;
}

// ---------------- repack W1,W2 (f32) into MFMA B-frag bf16 order ----------------
__global__ void repack_kernel(const float* __restrict__ W1, const float* __restrict__ W2,
                              unsigned short* __restrict__ W1p, unsigned short* __restrict__ W2p) {
  int i = blockIdx.x * 256 + threadIdx.x;
  if (i < 16 * 4 * 64 * 8) {  // W1: [128,256] -> ng(16) kk(4) lane(64) j(8)
    int j = i & 7, lane = (i >> 3) & 63, kk = (i >> 9) & 3, ng = i >> 11;
    int n = ng * 16 + (lane & 15);
    int k = kk * 32 + (lane >> 4) * 8 + j;
    W1p[i] = f2bf(W1[k * HC + n]);
  }
  int i2 = i - 16 * 4 * 64 * 8;
  if (i2 >= 0 && i2 < 4 * 8 * 64 * 8) {  // W2: [256,64] -> ng(4) kk(8) lane(64) j(8)
    int j = i2 & 7, lane = (i2 >> 3) & 63, kk = (i2 >> 9) & 7, ng = i2 >> 12;
    int n = ng * 16 + (lane & 15);
    int k = kk * 32 + (lane >> 4) * 8 + j;
    W2p[i2] = f2bf(W2[k * CDIM + n]);
  }
}

// ---------------- GEMM1 + fused als1/ald1 + fused fp8 shadow write -------------------
__global__ __launch_bounds__(256) void gemm1_kernel(const float* __restrict__ x,
                                                    const unsigned short* __restrict__ W1p,
                                                    const float* __restrict__ a_src,
                                                    const float* __restrict__ a_dst,
                                                    unsigned short* __restrict__ h1,
                                                    unsigned char* __restrict__ h1f8,
                                                    float* __restrict__ als,
                                                    float* __restrict__ ald) {
  __shared__ float sh_as[HC], sh_ad[HC];
  {
    int t = threadIdx.x;
    sh_as[t] = a_src[t];
    sh_ad[t] = a_dst[t];
  }
  __syncthreads();
  int wave = threadIdx.x >> 6, lane = threadIdx.x & 63;
  int tile = blockIdx.x * 4 + wave;
  if (tile >= NT1) return;
  int r0 = tile * 16, m = lane & 15, quad = lane >> 4;
  int row = r0 + m;
  short8 a[4];
#pragma unroll
  for (int kk = 0; kk < 4; kk++) {
    int kb = kk * 32 + quad * 8;
    float4 f0 = *(const float4*)(x + row * DIN + kb);
    float4 f1 = *(const float4*)(x + row * DIN + kb + 4);
    alignas(16) unsigned short tmp[8];
    tmp[0] = f2bf(f0.x); tmp[1] = f2bf(f0.y); tmp[2] = f2bf(f0.z); tmp[3] = f2bf(f0.w);
    tmp[4] = f2bf(f1.x); tmp[5] = f2bf(f1.y); tmp[6] = f2bf(f1.z); tmp[7] = f2bf(f1.w);
    a[kk] = *(const short8*)tmp;
  }
#pragma unroll
  for (int hg = 0; hg < 4; hg++) {
    float ps[4] = {0.f, 0.f, 0.f, 0.f};
    float pd[4] = {0.f, 0.f, 0.f, 0.f};
#pragma unroll
    for (int sub = 0; sub < 4; sub++) {
      int ng = hg * 4 + sub;
      f32x4 acc = {0.f, 0.f, 0.f, 0.f};
#pragma unroll
      for (int kk = 0; kk < 4; kk++) {
        short8 b = *(const short8*)(W1p + ((ng * 4 + kk) * 64 + lane) * 8);
        acc = __builtin_amdgcn_mfma_f32_16x16x32_bf16(a[kk], b, acc, 0, 0, 0);
      }
      int col = ng * 16 + m;
      float asv = sh_as[col], adv = sh_ad[col];
#pragma unroll
      for (int r = 0; r < 4; r++) {
        int rr = r0 + quad * 4 + r;
        h1[rr * HC + col] = f2bf(acc[r]);
        h1f8[rr * HC + col] = f2f8(acc[r]);
        ps[r] += acc[r] * asv;
        pd[r] += acc[r] * adv;
      }
    }
#pragma unroll
    for (int o = 1; o < 16; o <<= 1) {
#pragma unroll
      for (int r = 0; r < 4; r++) {
        ps[r] += __shfl_xor(ps[r], o, 64);
        pd[r] += __shfl_xor(pd[r], o, 64);
      }
    }
    if (m == 0) {
#pragma unroll
      for (int r = 0; r < 4; r++) {
        int rr = r0 + quad * 4 + r;
        als[rr * NHEAD + hg] = ps[r];
        ald[rr * NHEAD + hg] = pd[r];
      }
    }
  }
}

// ---------------- edge histogram (deg by dst, 8-way sharded by e&7) ----------------
__global__ void hist_kernel(const int* __restrict__ ei, int* __restrict__ deg8) {
  int i = blockIdx.x * 256 + threadIdx.x;
  if (i < NE) atomicAdd(&deg8[(i & 7) * NN + ei[NE + i]], 1);
}

// ---------------- exclusive scan of deg -> off, sharded cursors ----------------
__global__ void scan_a(const int* __restrict__ deg8, int* __restrict__ bsum,
                       int* __restrict__ degsum) {
  __shared__ int sm[256];
  int t = threadIdx.x, i = blockIdx.x * 256 + t;
  int d = 0;
  if (i < NN) {
#pragma unroll
    for (int j = 0; j < 8; j++) d += deg8[j * NN + i];
    degsum[i] = d;
  }
  sm[t] = d;
  __syncthreads();
  for (int s = 128; s > 0; s >>= 1) {
    if (t < s) sm[t] += sm[t + s];
    __syncthreads();
  }
  if (t == 0) bsum[blockIdx.x] = sm[0];
}
__global__ void scan_b(const int* __restrict__ bsum, int* __restrict__ bscan) {
  __shared__ int sm[256];
  int t = threadIdx.x;
  int own = (t < NB) ? bsum[t] : 0;
  sm[t] = own;
  __syncthreads();
  for (int s = 1; s < 256; s <<= 1) {
    int v = (t >= s) ? sm[t - s] : 0;
    __syncthreads();
    sm[t] += v;
    __syncthreads();
  }
  if (t < NB) bscan[t] = sm[t] - own;  // exclusive over block sums
}
__global__ void scan_c(const int* __restrict__ degsum, const int* __restrict__ deg8,
                       const int* __restrict__ bscan,
                       int* __restrict__ off, int* __restrict__ cursor8) {
  __shared__ int sm[256];
  int t = threadIdx.x, i = blockIdx.x * 256 + t;
  int d = (i < NN) ? degsum[i] : 0;
  sm[t] = d;
  __syncthreads();
  for (int s = 1; s < 256; s <<= 1) {
    int v = (t >= s) ? sm[t - s] : 0;
    __syncthreads();
    sm[t] += v;
    __syncthreads();
  }
  int excl = bscan[blockIdx.x] + sm[t] - d;
  if (i < NN) {
    off[i] = excl;
    int base = excl;
#pragma unroll
    for (int j = 0; j < 8; j++) {
      cursor8[j * NN + i] = base;
      base += deg8[j * NN + i];
    }
    if (i == NN - 1) off[NN] = excl + d;
  }
}

// ---------------- XCD-affine scatter: block (chunk c, xcd x) scatters only ----------
// edges with dst/6250 == x, so each CSR line is written by one XCD only.
// grid = 256 chunks * 8 = 2048 blocks; NE/256 = 3125 edges per chunk.
__global__ void scatter_kernel(const int* __restrict__ ei, int* __restrict__ cursor8,
                               int2* __restrict__ epair) {
  int xcd = blockIdx.x & 7;
  int chunk = blockIdx.x >> 3;
  int lo = chunk * (NE / 256);
  int hi = lo + (NE / 256);
  for (int e = lo + threadIdx.x; e < hi; e += 256) {
    int d = ei[NE + e];
    if (d / (NN / 8) == xcd) {
      int s = ei[e];
      int p = atomicAdd(&cursor8[(e & 7) * NN + d], 1);
      epair[p] = make_int2(s, d);
    }
  }
}

// ---------------- layer1 edge weights + dense esrc, CSR order, coalesced -------------
__global__ void ew1_kernel(const int2* __restrict__ epair,
                           const float* __restrict__ als, const float* __restrict__ ald,
                           float* __restrict__ ew, int* __restrict__ esrc) {
  int k = blockIdx.x * 256 + threadIdx.x;
  if (k >= NE) return;
  int2 e = epair[k];
  esrc[k] = e.x;
  float4 as = *(const float4*)(als + e.x * 4);
  float4 ad = *(const float4*)(ald + e.y * 4);
  float4 w;
  w.x = __expf(lrelu(as.x + ad.x));
  w.y = __expf(lrelu(as.y + ad.y));
  w.z = __expf(lrelu(as.z + ad.z));
  w.w = __expf(lrelu(as.w + ad.w));
  *(float4*)(ew + k * 4) = w;
}

// ---------------- GAT layer1 aggregation: wave/node, fp8 packed decode ---------------
// Single clamped 16-edge loop: 8 gathers always in flight (w=0 for out-of-range).
// lane -> edge-group eg=lane>>5 (2 groups), channels c0=(lane&31)*8 (8 ch, head c0>>6).
__global__ __launch_bounds__(256) void agg1_kernel(const unsigned short* __restrict__ h1,
                                                   const unsigned char* __restrict__ h1f8,
                                                   const float* __restrict__ als,
                                                   const float* __restrict__ ald,
                                                   const int* __restrict__ off,
                                                   const int* __restrict__ esrc,
                                                   const float* __restrict__ ew,
                                                   const float* __restrict__ b1,
                                                   unsigned short* __restrict__ out1) {
  int node = blockIdx.x * 4 + (threadIdx.x >> 6);
  int lane = threadIdx.x & 63;
  int eg = lane >> 5;
  int c0 = (lane & 31) * 8;
  int hh = c0 >> 6;
  int beg = off[node], end = off[node + 1];
  float a[8] = {0.f, 0.f, 0.f, 0.f, 0.f, 0.f, 0.f, 0.f};
  float zz = 0.f;
  for (int k = beg; k < end; k += 16) {
    int idx[8];
    int s[8];
    float w[8];
    uint2 u[8];
#pragma unroll
    for (int j = 0; j < 8; j++) {
      int i = k + 2 * j + eg;
      idx[j] = (i < end) ? i : beg;
    }
#pragma unroll
    for (int j = 0; j < 8; j++) s[j] = esrc[idx[j]];
#pragma unroll
    for (int j = 0; j < 8; j++) {
      float wv = ew[idx[j] * 4 + hh];
      w[j] = (k + 2 * j + eg < end) ? wv : 0.f;
      u[j] = *(const uint2*)(h1f8 + s[j] * HC + c0);
    }
#pragma unroll
    for (int j = 0; j < 8; j++) {
      f32x2 p0 = __builtin_amdgcn_cvt_pk_f32_fp8(u[j].x, false);
      f32x2 p1 = __builtin_amdgcn_cvt_pk_f32_fp8(u[j].x, true);
      f32x2 p2 = __builtin_amdgcn_cvt_pk_f32_fp8(u[j].y, false);
      f32x2 p3 = __builtin_amdgcn_cvt_pk_f32_fp8(u[j].y, true);
      a[0] += w[j] * p0.x; a[1] += w[j] * p0.y;
      a[2] += w[j] * p1.x; a[3] += w[j] * p1.y;
      a[4] += w[j] * p2.x; a[5] += w[j] * p2.y;
      a[6] += w[j] * p3.x; a[7] += w[j] * p3.y;
      zz += w[j];
    }
  }
  // combine the two edge-groups (lanes L and L^32 cover the same channels)
#pragma unroll
  for (int j = 0; j < 8; j++) a[j] += __shfl_xor(a[j], 32, 64);
  zz += __shfl_xor(zz, 32, 64);
  if (eg == 0) {
    // self-loop from bf16 original
    float sw = __expf(lrelu(als[node * NHEAD + hh] + ald[node * NHEAD + hh]));
    ushort4 vs0 = *(const ushort4*)(h1 + node * HC + c0);
    ushort4 vs1 = *(const ushort4*)(h1 + node * HC + c0 + 4);
    a[0] += sw * bf2f(vs0.x); a[1] += sw * bf2f(vs0.y);
    a[2] += sw * bf2f(vs0.z); a[3] += sw * bf2f(vs0.w);
    a[4] += sw * bf2f(vs1.x); a[5] += sw * bf2f(vs1.y);
    a[6] += sw * bf2f(vs1.z); a[7] += sw * bf2f(vs1.w);
    zz += sw;
    float inv = 1.f / zz;
    float4 bb0 = *(const float4*)(b1 + c0);
    float4 bb1 = *(const float4*)(b1 + c0 + 4);
    ushort4 o0, o1;
    o0.x = f2bf(a[0] * inv + bb0.x); o0.y = f2bf(a[1] * inv + bb0.y);
    o0.z = f2bf(a[2] * inv + bb0.z); o0.w = f2bf(a[3] * inv + bb0.w);
    o1.x = f2bf(a[4] * inv + bb1.x); o1.y = f2bf(a[5] * inv + bb1.y);
    o1.z = f2bf(a[6] * inv + bb1.z); o1.w = f2bf(a[7] * inv + bb1.w);
    *(ushort4*)(out1 + node * HC + c0) = o0;
    *(ushort4*)(out1 + node * HC + c0 + 4) = o1;
  }
}

// ---------------- BN stats over out1 ----------------
__global__ __launch_bounds__(256) void bnstats_kernel(const unsigned short* __restrict__ out1,
                                                      float* __restrict__ bnsum,
                                                      float* __restrict__ bnsumsq) {
  int t = threadIdx.x;
  float s = 0.f, s2 = 0.f;
  for (int r = blockIdx.x; r < NN; r += gridDim.x) {
    float v = bf2f(out1[r * HC + t]);
    s += v;
    s2 += v * v;
  }
  atomicAdd(&bnsum[t], s);
  atomicAdd(&bnsumsq[t], s2);
}

// ---------------- GEMM2 + fused als2/ald2: h2 = relu(bn(out1)) @ W2 ------------------
__global__ __launch_bounds__(256) void gemm2_kernel(const unsigned short* __restrict__ out1,
                                                    const unsigned short* __restrict__ W2p,
                                                    const float* __restrict__ bnsum,
                                                    const float* __restrict__ bnsumsq,
                                                    const float* __restrict__ gamma,
                                                    const float* __restrict__ beta,
                                                    const float* __restrict__ a_src2,
                                                    const float* __restrict__ a_dst2,
                                                    unsigned short* __restrict__ h2,
                                                    float* __restrict__ als2,
                                                    float* __restrict__ ald2) {
  __shared__ float scale_s[HC], shift_s[HC];
  __shared__ float sh_as[CDIM], sh_ad[CDIM];
  {
    int t = threadIdx.x;
    float mu = bnsum[t] / (float)NN;
    float var = bnsumsq[t] / (float)NN - mu * mu;
    float sc = gamma[t] * rsqrtf(var + 1e-5f);
    scale_s[t] = sc;
    shift_s[t] = beta[t] - mu * sc;
    if (t < CDIM) {
      sh_as[t] = a_src2[t];
      sh_ad[t] = a_dst2[t];
    }
  }
  __syncthreads();
  int wave = threadIdx.x >> 6, lane = threadIdx.x & 63;
  int tile = blockIdx.x * 4 + wave;
  if (tile >= NT1) return;
  int r0 = tile * 16, m = lane & 15, quad = lane >> 4;
  int row = r0 + m;
  short8 a[8];
#pragma unroll
  for (int kk = 0; kk < 8; kk++) {
    int kb = kk * 32 + quad * 8;
    short8 raw = *(const short8*)(out1 + row * HC + kb);
    alignas(16) unsigned short tmp[8];
#pragma unroll
    for (int j = 0; j < 8; j++) {
      tmp[j] = f2bf(relu(bf2f((unsigned short)raw[j]) * scale_s[kb + j] + shift_s[kb + j]));
    }
    a[kk] = *(const short8*)tmp;
  }
  float ps[4] = {0.f, 0.f, 0.f, 0.f};
  float pd[4] = {0.f, 0.f, 0.f, 0.f};
#pragma unroll
  for (int ng = 0; ng < 4; ng++) {
    f32x4 acc = {0.f, 0.f, 0.f, 0.f};
#pragma unroll
    for (int kk = 0; kk < 8; kk++) {
      short8 b = *(const short8*)(W2p + ((ng * 8 + kk) * 64 + lane) * 8);
      acc = __builtin_amdgcn_mfma_f32_16x16x32_bf16(a[kk], b, acc, 0, 0, 0);
    }
    int col = ng * 16 + m;
    float asv = sh_as[col], adv = sh_ad[col];
#pragma unroll
    for (int r = 0; r < 4; r++) {
      h2[(r0 + quad * 4 + r) * CDIM + col] = f2bf(acc[r]);
      ps[r] += acc[r] * asv;
      pd[r] += acc[r] * adv;
    }
  }
#pragma unroll
  for (int o = 1; o < 16; o <<= 1) {
#pragma unroll
    for (int r = 0; r < 4; r++) {
      ps[r] += __shfl_xor(ps[r], o, 64);
      pd[r] += __shfl_xor(pd[r], o, 64);
    }
  }
  if (m == 0) {
#pragma unroll
    for (int r = 0; r < 4; r++) {
      int rr = r0 + quad * 4 + r;
      als2[rr] = ps[r];
      ald2[rr] = pd[r];
    }
  }
}

// ---------------- layer2 edge weights, CSR order, coalesced ----------------
__global__ void ew2_kernel(const int2* __restrict__ epair,
                           const float* __restrict__ als2, const float* __restrict__ ald2,
                           float* __restrict__ ew2) {
  int k = blockIdx.x * 256 + threadIdx.x;
  if (k >= NE) return;
  int2 e = epair[k];
  ew2[k] = __expf(lrelu(als2[e.x] + ald2[e.y]));
}

// ---------------- GAT layer2 agg + ReLU + pooling: clamped 16-edge loop --------------
// lane -> half=lane>>5 (2 edge groups), channels cp=(lane&31)*2 (ushort2 bf16).
__global__ __launch_bounds__(256) void agg2_kernel(const unsigned short* __restrict__ h2,
                                                   const float* __restrict__ als2,
                                                   const float* __restrict__ ald2,
                                                   const int* __restrict__ off,
                                                   const int* __restrict__ esrc,
                                                   const float* __restrict__ ew2,
                                                   const float* __restrict__ b2,
                                                   const int* __restrict__ batch,
                                                   float* __restrict__ pooled) {
  int node = blockIdx.x * 4 + (threadIdx.x >> 6);
  int lane = threadIdx.x & 63;
  int half = lane >> 5;
  int cp = (lane & 31) * 2;
  int beg = off[node], end = off[node + 1];
  float a0 = 0.f, a1 = 0.f, zz = 0.f;
  for (int k = beg; k < end; k += 16) {
    int idx[8];
    int s[8];
    float w[8];
    ushort2 v[8];
#pragma unroll
    for (int j = 0; j < 8; j++) {
      int i = k + 2 * j + half;
      idx[j] = (i < end) ? i : beg;
    }
#pragma unroll
    for (int j = 0; j < 8; j++) s[j] = esrc[idx[j]];
#pragma unroll
    for (int j = 0; j < 8; j++) {
      float wv = ew2[idx[j]];
      w[j] = (k + 2 * j + half < end) ? wv : 0.f;
      v[j] = *(const ushort2*)(h2 + s[j] * CDIM + cp);
    }
#pragma unroll
    for (int j = 0; j < 8; j++) {
      a0 += w[j] * bf2f(v[j].x);
      a1 += w[j] * bf2f(v[j].y);
      zz += w[j];
    }
  }
  // combine the two halves (lanes L and L^32 cover the same channel pair)
  a0 += __shfl_xor(a0, 32, 64);
  a1 += __shfl_xor(a1, 32, 64);
  zz += __shfl_xor(zz, 32, 64);
  if (half == 0) {
    float sw = __expf(lrelu(als2[node] + ald2[node]));
    ushort2 vs = *(const ushort2*)(h2 + node * CDIM + cp);
    a0 += sw * bf2f(vs.x);
    a1 += sw * bf2f(vs.y);
    zz += sw;
    float inv = 1.f / zz;
    int g = batch[node];
    float v0 = relu(a0 * inv + b2[cp]);
    float v1 = relu(a1 * inv + b2[cp + 1]);
    atomicAdd(&pooled[g * CDIM + cp], v0);
    atomicAdd(&pooled[g * CDIM + cp + 1], v1);
  }
}

// ---------------- pooled mean + classifier (f32 output); counts via binary search ----
__global__ void cls_kernel(const float* __restrict__ pooled, const int* __restrict__ batch,
                           const float* __restrict__ cW1, const float* __restrict__ cb1,
                           const float* __restrict__ cW2, const float* __restrict__ cb2,
                           float* __restrict__ out) {
  __shared__ float p[64];
  __shared__ float z[32];
  int g = blockIdx.x, t = threadIdx.x;
  int lo = 0, hi = NN;
  while (lo < hi) { int mid = (lo + hi) >> 1; if (batch[mid] < g) lo = mid + 1; else hi = mid; }
  int start = lo;
  lo = 0; hi = NN;
  while (lo < hi) { int mid = (lo + hi) >> 1; if (batch[mid] <= g) lo = mid + 1; else hi = mid; }
  int c = lo - start;
  float cnt = (float)(c > 0 ? c : 1);
  p[t] = pooled[g * CDIM + t] / cnt;
  __syncthreads();
  if (t < 32) {
    float a = cb1[t];
    for (int k = 0; k < 64; k++) a += p[k] * cW1[k * 32 + t];
    z[t] = relu(a);
  }
  __syncthreads();
  if (t < NCLS) {
    float a = cb2[t];
    for (int k = 0; k < 32; k++) a += z[k] * cW2[k * NCLS + t];
    out[g * NCLS + t] = a;
  }
}

extern "C" void kernel_launch(void* const* d_in, const int* in_sizes, int n_in,
                              void* d_out, int out_size, void* d_ws, size_t ws_size,
                              hipStream_t stream) {
  const float* x = (const float*)d_in[0];
  const int* edge_index = (const int*)d_in[1];
  const int* batch = (const int*)d_in[2];
  const float* W1 = (const float*)d_in[3];
  const float* a_src1 = (const float*)d_in[4];
  const float* a_dst1 = (const float*)d_in[5];
  const float* b1 = (const float*)d_in[6];
  const float* gamma = (const float*)d_in[7];
  const float* beta = (const float*)d_in[8];
  const float* W2 = (const float*)d_in[9];
  const float* a_src2 = (const float*)d_in[10];
  const float* a_dst2 = (const float*)d_in[11];
  const float* b2 = (const float*)d_in[12];
  const float* cW1 = (const float*)d_in[13];
  const float* cb1 = (const float*)d_in[14];
  const float* cW2 = (const float*)d_in[15];
  const float* cb2 = (const float*)d_in[16];

  // ---- workspace layout ----
  // zero region (contiguous, zeroed every call): deg8 | bnsum | bnsumsq | pooled
  int* deg8 = (int*)d_ws;
  float* bnsum = (float*)(deg8 + 8 * NN);
  float* bnsumsq = bnsum + HC;
  float* pooled = bnsumsq + HC;
  const int ZWORDS = 8 * NN + HC + HC + NGRAPH * CDIM;
  char* p = (char*)(pooled + NGRAPH * CDIM);
  auto align256 = [&](char*& q) {
    size_t a = (size_t)(q - (char*)d_ws);
    a = (a + 255) & ~(size_t)255;
    q = (char*)d_ws + a;
  };
  align256(p);
  int* degsum = (int*)p;          p += (size_t)NN * 4;       align256(p);
  int* offs = (int*)p;            p += (size_t)(NN + 1) * 4; align256(p);
  int* cursor8 = (int*)p;         p += (size_t)8 * NN * 4;   align256(p);
  int2* epair = (int2*)p;         p += (size_t)NE * 8;       align256(p);
  int* esrc = (int*)p;            p += (size_t)NE * 4;       align256(p);
  int* bsum = (int*)p;            p += 256 * 4;              align256(p);
  int* bscan = (int*)p;           p += 256 * 4;              align256(p);
  // h1 region; ew2 (NE*4 = 3.2MB) aliases its head: h1 dead after agg1, ew2 written later
  unsigned short* h1 = (unsigned short*)p;
  float* ew2 = (float*)p;         p += (size_t)NN * HC * 2;   align256(p);
  unsigned short* out1 = (unsigned short*)p; p += (size_t)NN * HC * 2;   align256(p);
  unsigned short* h2 = (unsigned short*)p;   p += (size_t)NN * CDIM * 2; align256(p);
  float* als1 = (float*)p;        p += (size_t)NN * NHEAD * 4; align256(p);
  float* ald1 = (float*)p;        p += (size_t)NN * NHEAD * 4; align256(p);
  float* als2v = (float*)p;       p += (size_t)NN * 4;         align256(p);
  float* ald2v = (float*)p;       p += (size_t)NN * 4;         align256(p);
  float* ew1 = (float*)p;         p += (size_t)NE * NHEAD * 4; align256(p);
  unsigned char* h1f8 = (unsigned char*)p; p += (size_t)NN * HC;        align256(p);
  unsigned short* W1p = (unsigned short*)p; p += 32768 * 2;    align256(p);
  unsigned short* W2p = (unsigned short*)p; p += 16384 * 2;    align256(p);

  zero_kernel<<<(ZWORDS + 255) / 256, 256, 0, stream>>>((int*)d_ws, ZWORDS);
  repack_kernel<<<192, 256, 0, stream>>>(W1, W2, W1p, W2p);
  gemm1_kernel<<<(NT1 + 3) / 4, 256, 0, stream>>>(x, W1p, a_src1, a_dst1, h1, h1f8,
                                                  als1, ald1);
  hist_kernel<<<(NE + 255) / 256, 256, 0, stream>>>(edge_index, deg8);
  scan_a<<<NB, 256, 0, stream>>>(deg8, bsum, degsum);
  scan_b<<<1, 256, 0, stream>>>(bsum, bscan);
  scan_c<<<NB, 256, 0, stream>>>(degsum, deg8, bscan, offs, cursor8);
  scatter_kernel<<<2048, 256, 0, stream>>>(edge_index, cursor8, epair);
  ew1_kernel<<<(NE + 255) / 256, 256, 0, stream>>>(epair, als1, ald1, ew1, esrc);
  agg1_kernel<<<NN / 4, 256, 0, stream>>>(h1, h1f8, als1, ald1, offs, esrc, ew1, b1, out1);
  bnstats_kernel<<<1024, 256, 0, stream>>>(out1, bnsum, bnsumsq);
  gemm2_kernel<<<(NT1 + 3) / 4, 256, 0, stream>>>(out1, W2p, bnsum, bnsumsq, gamma, beta,
                                                  a_src2, a_dst2, h2, als2v, ald2v);
  ew2_kernel<<<(NE + 255) / 256, 256, 0, stream>>>(epair, als2v, ald2v, ew2);
  agg2_kernel<<<NN / 4, 256, 0, stream>>>(h2, als2v, ald2v, offs, esrc, ew2, b2,
                                          batch, pooled);
  cls_kernel<<<NGRAPH, 64, 0, stream>>>(pooled, batch, cW1, cb1, cW2, cb2, (float*)d_out);
}